// Round 4
// baseline (1163.375 us; speedup 1.0000x reference)
//
#include <hip/hip_runtime.h>

#define PI_D 3.14159265358979323846
#define BATCH 1024
#define NOISE_K 13
#define N_ANGLES 360

// ---------------- ws layout (float offsets) ----------------
#define WS_BNA    0                         // 512
#define WS_BNB    (WS_BNA + 512)            // 512
#define WS_H      (WS_BNB + 512)            // 1024*32
#define WS_RX     (WS_H + BATCH*32)         // 1024*512
#define WS_CA     (WS_RX + BATCH*512)       // 360*16*2
#define WS_FC1T   (WS_CA + N_ANGLES*16*2)   // 360*32
#define WS_UN     (WS_FC1T + N_ANGLES*32)   // 1024*13*16*2

// ================= complex float helpers =================
__device__ __forceinline__ float2 f2(float a, float b){ return make_float2(a,b); }
__device__ __forceinline__ float2 fadd2(float2 a, float2 b){ return f2(a.x+b.x, a.y+b.y); }
__device__ __forceinline__ float2 fsub2(float2 a, float2 b){ return f2(a.x-b.x, a.y-b.y); }
__device__ __forceinline__ float2 fmul2(float2 a, float2 b){ return f2(a.x*b.x - a.y*b.y, a.x*b.y + a.y*b.x); }
__device__ __forceinline__ float2 fconj2(float2 a){ return f2(a.x, -a.y); }
__device__ __forceinline__ float2 fscale2(float2 a, float s){ return f2(a.x*s, a.y*s); }
__device__ __forceinline__ float  fabs2sq(float2 a){ return a.x*a.x + a.y*a.y; }
__device__ __forceinline__ float2 fmad2(float2 b, float2 c, float2 a){ return fadd2(a, fmul2(b,c)); }
__device__ __forceinline__ float2 fdivc2(float2 a, float2 b){
  float id = __frcp_rn(b.x*b.x + b.y*b.y);
  return f2((a.x*b.x + a.y*b.y)*id, (a.y*b.x - a.x*b.y)*id);
}
__device__ __forceinline__ float2 csqrtf2(float2 z){
  float m = __fsqrt_rn(z.x*z.x + z.y*z.y);
  if (m == 0.f) return f2(0.f, 0.f);
  float u = __fsqrt_rn(0.5f*(m + fabsf(z.x)));
  if (z.x >= 0.f) return f2(u, z.y/(2.f*u));
  float v = (z.y >= 0.f) ? u : -u;
  return f2(z.y/(2.f*v), v);
}
__device__ __forceinline__ float2 shfl2(float2 v, int src){
  return f2(__shfl(v.x, src, 64), __shfl(v.y, src, 64));
}

// ================= prep: conj(A) table + fc1 transpose =================
__global__ void prep_kernel(const float* __restrict__ fc1W, float* __restrict__ CA,
                            float* __restrict__ fc1T){
  int i = blockIdx.x*256 + threadIdx.x;
  if (i < N_ANGLES*16){
    int a = i >> 4, n = i & 15;
    float ang = (float)(-PI_D*0.5 + (double)a * (PI_D/359.0));
    float ph = (float)PI_D * (float)n * sinf(ang);
    CA[2*i]   = cosf(ph);   // conj(A) = cos + i sin
    CA[2*i+1] = sinf(ph);
  }
  if (i < N_ANGLES*32){
    int a = i >> 5, j = i & 31;
    fc1T[i] = fc1W[j*N_ANGLES + a];   // fc1T[a][j]
  }
}

// ================= batchnorm stats over (B, C) per t' =================
__global__ __launch_bounds__(256) void bn_stats_kernel(
    const float* __restrict__ Xr, const float* __restrict__ Xi,
    const float* __restrict__ bnw, const float* __restrict__ bnb,
    float* __restrict__ bnA, float* __restrict__ bnB){
  const int tp = blockIdx.x;                 // feature t' in [0,512)
  const int n = tp >> 4;
  const float* src = (n < 16) ? Xr : Xi;
  const size_t roff = (size_t)(n & 15)*512 + (size_t)(tp & 15)*32;
  const int c4 = threadIdx.x & 7;            // float4 index within the 32-float run
  const int bg = threadIdx.x >> 3;           // 0..31
  double s = 0.0, ss = 0.0;
  for (int i = 0; i < 32; i++){
    int b = bg*32 + i;
    const float4 v = *(const float4*)(src + (size_t)b*8192 + roff + c4*4);
    s  += (double)v.x + (double)v.y + (double)v.z + (double)v.w;
    ss += (double)v.x*v.x + (double)v.y*v.y + (double)v.z*v.z + (double)v.w*v.w;
  }
  for (int m=1; m<64; m<<=1){ s += __shfl_xor(s, m, 64); ss += __shfl_xor(ss, m, 64); }
  __shared__ double sh[4][2];
  int wid = threadIdx.x >> 6, lane = threadIdx.x & 63;
  if (lane == 0){ sh[wid][0] = s; sh[wid][1] = ss; }
  __syncthreads();
  if (threadIdx.x == 0){
    double S  = sh[0][0]+sh[1][0]+sh[2][0]+sh[3][0];
    double SS = sh[0][1]+sh[1][1]+sh[2][1]+sh[3][1];
    double mean = S/32768.0;
    double var  = SS/32768.0 - mean*mean;
    double inv  = 1.0/sqrt(var + 1e-5);
    double a = (double)bnw[tp]*inv;
    bnA[tp] = (float)a;
    bnB[tp] = (float)((double)bnb[tp] - mean*a);
  }
}

// ================= fused BN-apply + GRU (64 lanes per batch elem) =================
// BN pre-applied at LDS staging. rcp-based gates. h via wave-private LDS broadcast.
__global__ __launch_bounds__(256) void gru_kernel(
    const float* __restrict__ Xr, const float* __restrict__ Xi,
    const float* __restrict__ Wih, const float* __restrict__ Whh,
    const float* __restrict__ bih, const float* __restrict__ bhh,
    const float* __restrict__ bnA, const float* __restrict__ bnB,
    float* __restrict__ hbuf){
  const int lane = threadIdx.x & 63;
  const int wv   = threadIdx.x >> 6;
  const int b    = blockIdx.x*4 + wv;
  const int j    = lane & 31;      // output index
  const int k0   = (lane >> 5)*16; // this lane's k-half
  const int tt0  = lane >> 3;      // 0..7 : step-within-chunk of first float4
  __shared__ float xb[4][2][512];
  __shared__ float hl[4][32];

  float WI0[16], WI1[16], WI2[16], WH0[16], WH1[16], WH2[16];
  #pragma unroll
  for (int kk=0; kk<16; kk++){
    WI0[kk] = Wih[(j     )*32 + k0+kk];
    WI1[kk] = Wih[(32+j  )*32 + k0+kk];
    WI2[kk] = Wih[(64+j  )*32 + k0+kk];
    WH0[kk] = Whh[(j     )*32 + k0+kk];
    WH1[kk] = Whh[(32+j  )*32 + k0+kk];
    WH2[kk] = Whh[(64+j  )*32 + k0+kk];
  }
  const float br  = bih[j]    + bhh[j];
  const float bz  = bih[32+j] + bhh[32+j];
  const float bin = bih[64+j];
  const float bhn = bhh[64+j];
  const size_t xbase = (size_t)b*8192;

  // prologue: chunk 0 = Xr row 0, BN applied at store
  {
    const float* s0 = Xr + xbase;
    float4 p0 = *(const float4*)(s0 + lane*4);
    float4 p1 = *(const float4*)(s0 + 256 + lane*4);
    const float a0 = bnA[tt0],   b0 = bnB[tt0];
    const float a1 = bnA[8+tt0], b1 = bnB[8+tt0];
    p0.x = fmaf(p0.x,a0,b0); p0.y = fmaf(p0.y,a0,b0); p0.z = fmaf(p0.z,a0,b0); p0.w = fmaf(p0.w,a0,b0);
    p1.x = fmaf(p1.x,a1,b1); p1.y = fmaf(p1.y,a1,b1); p1.z = fmaf(p1.z,a1,b1); p1.w = fmaf(p1.w,a1,b1);
    *(float4*)&xb[wv][0][lane*4]       = p0;
    *(float4*)&xb[wv][0][256 + lane*4] = p1;
  }
  hl[wv][j] = 0.f;   // lanes j and j+32 write same value: benign
  float h = 0.f;

  for (int m=0; m<32; m++){
    float4 q0, q1; float a0n=0.f,b0n=0.f,a1n=0.f,b1n=0.f;
    if (m < 31){
      const int mm = m+1;
      const float* s2 = ((mm < 16) ? Xr : Xi) + xbase + (size_t)(mm & 15)*512;
      q0 = *(const float4*)(s2 + lane*4);
      q1 = *(const float4*)(s2 + 256 + lane*4);
      a0n = bnA[mm*16+tt0];   b0n = bnB[mm*16+tt0];
      a1n = bnA[mm*16+8+tt0]; b1n = bnB[mm*16+8+tt0];
    }
    const float* xc = xb[wv][m & 1];
    for (int tt=0; tt<16; tt++){
      // h broadcast read first (long-latency op on the recurrent chain)
      const float4 ha = *(const float4*)&hl[wv][k0];
      const float4 hb = *(const float4*)&hl[wv][k0 + 4];
      const float4 hc = *(const float4*)&hl[wv][k0 + 8];
      const float4 hd = *(const float4*)&hl[wv][k0 + 12];
      // x-dots (independent of h -> fills LDS latency)
      const float4 xa = *(const float4*)&xc[tt*32 + k0];
      const float4 xb2= *(const float4*)&xc[tt*32 + k0 + 4];
      const float4 xc2= *(const float4*)&xc[tt*32 + k0 + 8];
      const float4 xd = *(const float4*)&xc[tt*32 + k0 + 12];
      float xr16[16] = {xa.x,xa.y,xa.z,xa.w, xb2.x,xb2.y,xb2.z,xb2.w,
                        xc2.x,xc2.y,xc2.z,xc2.w, xd.x,xd.y,xd.z,xd.w};
      float gxr=0.f, gxz=0.f, gxn=0.f;
      #pragma unroll
      for (int kk=0; kk<16; kk++){
        gxr = fmaf(xr16[kk], WI0[kk], gxr);
        gxz = fmaf(xr16[kk], WI1[kk], gxz);
        gxn = fmaf(xr16[kk], WI2[kk], gxn);
      }
      float hr16[16] = {ha.x,ha.y,ha.z,ha.w, hb.x,hb.y,hb.z,hb.w,
                        hc.x,hc.y,hc.z,hc.w, hd.x,hd.y,hd.z,hd.w};
      float ghr=0.f, ghz=0.f, ghn=0.f;
      #pragma unroll
      for (int kk=0; kk<16; kk++){
        ghr = fmaf(hr16[kk], WH0[kk], ghr);
        ghz = fmaf(hr16[kk], WH1[kk], ghz);
        ghn = fmaf(hr16[kk], WH2[kk], ghn);
      }
      float grt = gxr + ghr;
      float gzt = gxz + ghz;
      grt += __shfl_xor(grt, 32, 64);
      gzt += __shfl_xor(gzt, 32, 64);
      float gnx = gxn + __shfl_xor(gxn, 32, 64);
      float hnv = ghn + __shfl_xor(ghn, 32, 64);
      const float r = __frcp_rn(1.0f + __expf(-(grt + br)));
      const float z = __frcp_rn(1.0f + __expf(-(gzt + bz)));
      const float nn = gnx + bin + r*(hnv + bhn);
      const float th = 1.0f - 2.0f*__frcp_rn(1.0f + __expf(2.0f*nn));  // tanh
      h = th + z*(h - th);
      hl[wv][j] = h;   // both halves write identical value
    }
    if (m < 31){
      q0.x = fmaf(q0.x,a0n,b0n); q0.y = fmaf(q0.y,a0n,b0n); q0.z = fmaf(q0.z,a0n,b0n); q0.w = fmaf(q0.w,a0n,b0n);
      q1.x = fmaf(q1.x,a1n,b1n); q1.y = fmaf(q1.y,a1n,b1n); q1.z = fmaf(q1.z,a1n,b1n); q1.w = fmaf(q1.w,a1n,b1n);
      *(float4*)&xb[wv][(m+1)&1][lane*4]       = q0;
      *(float4*)&xb[wv][(m+1)&1][256 + lane*4] = q1;
    }
  }
  if (lane < 32) hbuf[(size_t)b*32 + j] = h;
}

// ================= h -> Rx (K matrix entries) =================
__global__ __launch_bounds__(256) void rx_kernel(
    const float* __restrict__ hbuf, const float* __restrict__ fcW,
    const float* __restrict__ fcb, float* __restrict__ Rx){
  const int b = blockIdx.x;
  __shared__ float hs[32];
  if (threadIdx.x < 32) hs[threadIdx.x] = hbuf[(size_t)b*32 + threadIdx.x];
  __syncthreads();
  for (int o = threadIdx.x; o < 512; o += 256){
    float acc = fcb[o];
    const float4* W4 = (const float4*)(fcW + o*32);
    const float4* H4 = (const float4*)hs;
    #pragma unroll
    for (int q=0; q<8; q++){
      const float4 w = W4[q], hh = H4[q];
      acc += w.x*hh.x + w.y*hh.y + w.z*hh.z + w.w*hh.w;
    }
    Rx[(size_t)b*512 + o] = acc;
  }
}

// ================= complex 16x16 eig, fp32, one wave per matrix ================
// Single-wave block: LDS ops complete in program order across the wave -> no
// __syncthreads needed; wave_barrier() is a free compiler scheduling fence.
#define LD 17
__global__ __launch_bounds__(64) void eig_kernel(
    const float* __restrict__ Rx, float* __restrict__ Un){
  __shared__ float2 T[16*LD];
  __shared__ float2 Q[16*LD];
  __shared__ float2 Y[16*LD];
  __shared__ float2 ev[16];
  const int lane = threadIdx.x;
  const int b = blockIdx.x;
  const float* rx = Rx + (size_t)b*512;

  float hn2;
  {
    const float4 re = *(const float4*)(rx + lane*4);
    const float4 im = *(const float4*)(rx + 256 + lane*4);
    const float rr[4] = {re.x, re.y, re.z, re.w};
    const float ii[4] = {im.x, im.y, im.z, im.w};
    #pragma unroll
    for (int q=0; q<4; q++){
      const int e = lane*4 + q;
      const int r = e >> 4, c = e & 15;
      T[r*LD+c] = f2(rr[q], ii[q]);
      Q[r*LD+c] = f2((r==c)?1.f:0.f, 0.f);
    }
    float hp = rr[0]*rr[0]+rr[1]*rr[1]+rr[2]*rr[2]+rr[3]*rr[3]
             + ii[0]*ii[0]+ii[1]*ii[1]+ii[2]*ii[2]+ii[3]*ii[3];
    for (int m=1; m<64; m<<=1) hp += __shfl_xor(hp, m, 64);
    hn2 = (hp == 0.f) ? 1.f : hp;
  }
  __builtin_amdgcn_wave_barrier();

  // ---- Householder Hessenberg, accumulating Q ----
  for (int k=0; k<14; k++){
    float2 xr = f2(0.f,0.f);
    if (lane >= k+1 && lane < 16) xr = T[lane*LD+k];
    float nx2 = fabs2sq(xr);
    nx2 += __shfl_xor(nx2, 1, 64);
    nx2 += __shfl_xor(nx2, 2, 64);
    nx2 += __shfl_xor(nx2, 4, 64);
    nx2 += __shfl_xor(nx2, 8, 64);
    nx2 = __shfl(nx2, lane & 15, 64);   // broadcast group sum
    if (nx2 > 1e-30f){
      const float2 alpha = T[(k+1)*LD+k];
      const float anorm = __fsqrt_rn(fabs2sq(alpha));
      const float normx = __fsqrt_rn(nx2);
      const float2 beta = (anorm > 0.f) ? fscale2(alpha, -normx/anorm) : f2(-normx, 0.f);
      const float vn2 = 2.f*nx2 + 2.f*normx*anorm;
      const float inv = __frsqrt_rn(vn2);
      float2 wvl = fscale2(xr, inv);
      if (lane == k+1) wvl = fscale2(fsub2(xr, beta), inv);
      if (lane < 16) ev[lane] = (lane >= k+1) ? wvl : f2(0.f,0.f);
      __builtin_amdgcn_wave_barrier();
      if (lane < 16){   // left: column j = lane
        float2 d = f2(0.f,0.f);
        for (int r=k+1; r<16; r++) d = fmad2(fconj2(ev[r]), T[r*LD+lane], d);
        d = fscale2(d, 2.f);
        for (int r=k+1; r<16; r++) T[r*LD+lane] = fsub2(T[r*LD+lane], fmul2(ev[r], d));
      }
      __builtin_amdgcn_wave_barrier();
      if (lane < 32){   // right: rows of T (lanes 0-15) and Q (lanes 16-31)
        const int r0 = lane & 15;
        float2* M = (lane < 16) ? T : Q;
        float2 d = f2(0.f,0.f);
        for (int r=k+1; r<16; r++) d = fmad2(M[r0*LD+r], ev[r], d);
        d = fscale2(d, 2.f);
        for (int r=k+1; r<16; r++) M[r0*LD+r] = fsub2(M[r0*LD+r], fmul2(d, fconj2(ev[r])));
      }
      __builtin_amdgcn_wave_barrier();
    }
  }

  // ---- shifted QR: sticky-flag deflation, register-carried bulge chase ----
  unsigned long long deflmask = 0ull;
  int hi = 15, its = 0;
  const float eps2f = 1e-11f;    // (|sd|/|sc|)^2 threshold ~ (3.2e-6)^2
  for (int tot=0; tot<150; tot++){
    float2 sub = f2(0.f,0.f), dd0 = f2(0.f,0.f), dd1 = f2(0.f,0.f), sup = f2(0.f,0.f);
    if (lane >= 1 && lane < 16){
      sub = T[lane*LD+lane-1];
      dd0 = T[(lane-1)*LD+(lane-1)];
      dd1 = T[lane*LD+lane];
      sup = T[(lane-1)*LD+lane];
    }
    float sc2 = fabs2sq(dd0) + fabs2sq(dd1);
    if (sc2 == 0.f) sc2 = hn2;
    const bool fdef = (lane >= 1 && lane < 16) && (fabs2sq(sub) <= eps2f*sc2);
    deflmask |= __ballot(fdef);
    while (hi > 0 && ((deflmask >> hi) & 1ull)){ hi--; its = 0; }
    if (hi <= 0) break;
    const unsigned long long m2 = deflmask & ((1ull << hi) - 1ull);
    const int lo = m2 ? (63 - __builtin_clzll(m2)) : 0;
    its++;
    // window corners gathered from scan registers (no extra LDS reads)
    const float2 aa = shfl2(dd0, hi);
    const float2 bb = shfl2(sup, hi);
    const float2 cc = shfl2(sub, hi);
    const float2 dd = shfl2(dd1, hi);
    float2 mu;
    if (its % 10 == 0){
      mu = f2(dd.x + 0.75f*__fsqrt_rn(fabs2sq(cc)), dd.y);   // exceptional
    } else {
      const float2 t2 = fscale2(fsub2(aa, dd), 0.5f);
      const float2 bc = fmul2(bb, cc);
      const float2 del = csqrtf2(fadd2(fmul2(t2, t2), bc));
      const float2 d1 = fadd2(t2, del), d2v = fsub2(t2, del);
      const float2 den = (fabs2sq(d1) >= fabs2sq(d2v)) ? d1 : d2v;
      mu = (fabs2sq(den) > 0.f) ? fsub2(dd, fdivc2(bc, den)) : dd;
    }
    float2 x = fsub2(shfl2(dd0, lo+1), mu);
    float2 y = shfl2(sub, lo+1);
    for (int i=lo; i<hi; i++){
      // prefetch 2x2 entries (pre-rotation values; ordered after prev writes)
      const float2 t00 = T[i*LD+i],     t01 = T[i*LD+i+1];
      const float2 t10 = T[(i+1)*LD+i], t11 = T[(i+1)*LD+i+1];
      // role partition: 0 = row-update, 1 = T col-update, 2 = Q col-update, 3 = 2x2 writers
      const int q16 = lane & 15;
      const int role = lane >> 4;
      float2* Mp = (role == 2) ? Q : T;
      int ia, ib; bool active;
      if (role == 0){ ia = i*LD+q16; ib = (i+1)*LD+q16; active = (q16!=i)&&(q16!=i+1); }
      else if (role == 2){ ia = q16*LD+i; ib = ia+1; active = true; }
      else if (role == 1){ ia = q16*LD+i; ib = ia+1; active = (q16!=i)&&(q16!=i+1); }
      else { ia = 0; ib = 0; active = false; }
      float2 A = f2(0.f,0.f), B = f2(0.f,0.f);
      if (active){ A = Mp[ia]; B = Mp[ib]; }
      // rotation (all lanes, redundant)
      const float ax2 = fabs2sq(x), ay2 = fabs2sq(y);
      float c_; float2 s;
      if (ax2 < 1e-30f){
        if (ay2 < 1e-37f){ c_ = 1.f; s = f2(0.f,0.f); }
        else { c_ = 0.f; s = fscale2(fconj2(y), __frsqrt_rn(ay2)); }
      } else {
        const float inv_ax = __frsqrt_rn(ax2);
        const float inv_rr = __frsqrt_rn(ax2 + ay2);
        c_ = ax2*inv_ax*inv_rr;   // = |x| / r
        s = fscale2(fmul2(x, fconj2(y)), inv_ax*inv_rr);
      }
      float2 newA = f2(0.f,0.f);
      if (active){
        const float2 sl = (role == 0) ? s : fconj2(s);
        newA = fadd2(fscale2(A, c_), fmul2(sl, B));
        const float2 newB = fsub2(fscale2(B, c_), fmul2(fconj2(sl), A));
        Mp[ia] = newA;
        Mp[ib] = newB;
      }
      // 2x2 intersection G * T2 * G^H computed redundantly in-register by all lanes
      const float2 r0c0 = fadd2(fscale2(t00, c_), fmul2(s, t10));
      const float2 r0c1 = fadd2(fscale2(t01, c_), fmul2(s, t11));
      const float2 r1c0 = fsub2(fscale2(t10, c_), fmul2(fconj2(s), t00));
      const float2 r1c1 = fsub2(fscale2(t11, c_), fmul2(fconj2(s), t01));
      const float2 n00 = fadd2(fscale2(r0c0, c_), fmul2(fconj2(s), r0c1));
      const float2 n01 = fsub2(fscale2(r0c1, c_), fmul2(s, r0c0));
      const float2 n10 = fadd2(fscale2(r1c0, c_), fmul2(fconj2(s), r1c1));
      const float2 n11 = fsub2(fscale2(r1c1, c_), fmul2(s, r1c0));
      if (role == 3 && q16 < 4){
        const float2 val = (q16==0) ? n00 : (q16==1) ? n01 : (q16==2) ? n10 : n11;
        T[(i+(q16>>1))*LD + (i+(q16&1))] = val;
      }
      __builtin_amdgcn_wave_barrier();
      if (i < hi-1){
        x = n10;                      // new T[i+1][i], already in-register
        y = shfl2(newA, 18+i);        // role-1 lane q16=i+2: new T[i+2][i]
      }
    }
  }
  __builtin_amdgcn_wave_barrier();

  // ---- eigenvectors: backsolve on triangular T, then V = Q*Y ----
  if (lane < 16) ev[lane] = T[lane*LD+lane];
  __builtin_amdgcn_wave_barrier();
  const float hnf = __fsqrt_rn(hn2);
  const float smin = 1e-6f*hnf + 1e-35f;
  if (lane < 16){
    const int i = lane;
    const float2 lam = ev[i];
    Y[i*LD+i] = f2(1.f, 0.f);
    for (int jj=i-1; jj>=0; jj--){
      float2 sum = f2(0.f,0.f);
      for (int k2=jj+1; k2<=i; k2++) sum = fmad2(T[jj*LD+k2], Y[k2*LD+i], sum);
      float2 den = fsub2(T[jj*LD+jj], lam);
      if (fabs2sq(den) < smin*smin) den = f2(smin, 0.f);
      Y[jj*LD+i] = fdivc2(f2(-sum.x, -sum.y), den);
    }
  }
  __builtin_amdgcn_wave_barrier();
  {
    const int i = lane & 15;       // eigenvector index
    const int g = lane >> 4;       // row-group: rows 4g..4g+3
    float2 v[4]; float nrm = 0.f;
    #pragma unroll
    for (int q=0; q<4; q++){
      const int n = 4*g + q;
      float2 acc = f2(0.f,0.f);
      for (int k2=0; k2<=i; k2++) acc = fmad2(Q[n*LD+k2], Y[k2*LD+i], acc);
      v[q] = acc; nrm += fabs2sq(acc);
    }
    nrm += __shfl_xor(nrm, 16, 64);
    nrm += __shfl_xor(nrm, 32, 64);
    const float inv = __frsqrt_rn(nrm);
    const float mi = fabs2sq(ev[i]);
    int rank = 0;
    for (int k2=0; k2<16; k2++){
      const float mk = fabs2sq(ev[k2]);
      rank += (mk > mi) || (mk == mi && k2 > i);
    }
    if (rank >= 3){
      float* dst = Un + ((size_t)b*NOISE_K + (rank-3))*32 + 8*g;
      float4 w0, w1;
      w0.x = v[0].x*inv; w0.y = v[0].y*inv;
      w0.z = v[1].x*inv; w0.w = v[1].y*inv;
      w1.x = v[2].x*inv; w1.y = v[2].y*inv;
      w1.z = v[3].x*inv; w1.w = v[3].y*inv;
      ((float4*)dst)[0] = w0;
      ((float4*)dst)[1] = w1;
    }
  }
}

// ================= MUSIC spectrum + MLP head =================
__global__ __launch_bounds__(256) void spec_head_kernel(
    const float* __restrict__ Un, const float* __restrict__ CA,
    const float* __restrict__ fc1T, const float* __restrict__ fc1b,
    const float* __restrict__ fc2W, const float* __restrict__ fc2b,
    const float* __restrict__ fc3W, const float* __restrict__ fc3b,
    float* __restrict__ out){
  const int b = blockIdx.x;
  const int tid = threadIdx.x;
  __shared__ float2 Us[NOISE_K*16];
  __shared__ float spec[N_ANGLES];
  __shared__ float y1[32], y2[32];
  if (tid < NOISE_K*16) Us[tid] = ((const float2*)Un)[(size_t)b*NOISE_K*16 + tid];
  __syncthreads();
  for (int a = tid; a < N_ANGLES; a += 256){
    float sr[NOISE_K], si[NOISE_K];
    #pragma unroll
    for (int k=0; k<NOISE_K; k++){ sr[k]=0.f; si[k]=0.f; }
    for (int n=0; n<16; n++){
      float2 ca = ((const float2*)CA)[a*16+n];
      #pragma unroll
      for (int k=0; k<NOISE_K; k++){
        float2 u = Us[k*16+n];
        sr[k] += ca.x*u.x - ca.y*u.y;
        si[k] += ca.x*u.y + ca.y*u.x;
      }
    }
    float d = 0.f;
    #pragma unroll
    for (int k=0; k<NOISE_K; k++) d += sr[k]*sr[k] + si[k]*si[k];
    spec[a] = 1.0f/d;
  }
  __syncthreads();
  if (tid < 32){
    float acc = fc1b[tid];
    for (int a=0; a<N_ANGLES; a++) acc += spec[a]*fc1T[a*32+tid];
    y1[tid] = fmaxf(acc, 0.f);
  }
  __syncthreads();
  if (tid < 32){
    float acc = fc2b[tid];
    #pragma unroll
    for (int k=0; k<32; k++) acc += y1[k]*fc2W[tid*32+k];
    y2[tid] = fmaxf(acc, 0.f);
  }
  __syncthreads();
  if (tid < 32){
    float acc = fc2b[tid];
    #pragma unroll
    for (int k=0; k<32; k++) acc += y2[k]*fc2W[tid*32+k];
    y1[tid] = fmaxf(acc, 0.f);
  }
  __syncthreads();
  if (tid < 3){
    float acc = fc3b[tid];
    #pragma unroll
    for (int k=0; k<32; k++) acc += y1[k]*fc3W[tid*32+k];
    out[(size_t)b*3 + tid] = acc;
  }
}

// ================= launcher =================
extern "C" void kernel_launch(void* const* d_in, const int* in_sizes, int n_in,
                              void* d_out, int out_size, void* d_ws, size_t ws_size,
                              hipStream_t stream){
  (void)in_sizes; (void)n_in; (void)out_size; (void)ws_size;
  const float* Xr   = (const float*)d_in[0];
  const float* Xi   = (const float*)d_in[1];
  const float* bnw  = (const float*)d_in[2];
  const float* bnb  = (const float*)d_in[3];
  const float* Wih  = (const float*)d_in[4];
  const float* Whh  = (const float*)d_in[5];
  const float* bih  = (const float*)d_in[6];
  const float* bhh  = (const float*)d_in[7];
  const float* fcW  = (const float*)d_in[8];
  const float* fcb  = (const float*)d_in[9];
  const float* fc1W = (const float*)d_in[10];
  const float* fc1b = (const float*)d_in[11];
  const float* fc2W = (const float*)d_in[12];
  const float* fc2b = (const float*)d_in[13];
  const float* fc3W = (const float*)d_in[14];
  const float* fc3b = (const float*)d_in[15];

  float* ws   = (float*)d_ws;
  float* bnA  = ws + WS_BNA;
  float* bnB  = ws + WS_BNB;
  float* hbuf = ws + WS_H;
  float* RxB  = ws + WS_RX;
  float* CA   = ws + WS_CA;
  float* fc1T = ws + WS_FC1T;
  float* UnB  = ws + WS_UN;

  hipLaunchKernelGGL(prep_kernel, dim3(45), dim3(256), 0, stream, fc1W, CA, fc1T);
  hipLaunchKernelGGL(bn_stats_kernel, dim3(512), dim3(256), 0, stream,
                     Xr, Xi, bnw, bnb, bnA, bnB);
  hipLaunchKernelGGL(gru_kernel, dim3(256), dim3(256), 0, stream,
                     Xr, Xi, Wih, Whh, bih, bhh, bnA, bnB, hbuf);
  hipLaunchKernelGGL(rx_kernel, dim3(1024), dim3(256), 0, stream,
                     hbuf, fcW, fcb, RxB);
  hipLaunchKernelGGL(eig_kernel, dim3(1024), dim3(64), 0, stream, RxB, UnB);
  hipLaunchKernelGGL(spec_head_kernel, dim3(1024), dim3(256), 0, stream,
                     UnB, CA, fc1T, fc1b, fc2W, fc2b, fc3W, fc3b, (float*)d_out);
}

// Round 5
// 934.350 us; speedup vs baseline: 1.2451x; 1.2451x over previous
//
#include <hip/hip_runtime.h>

#define PI_D 3.14159265358979323846
#define BATCH 1024
#define NOISE_K 13
#define N_ANGLES 360

// ---------------- ws layout (float offsets) ----------------
#define WS_BNA    0                         // 512
#define WS_BNB    (WS_BNA + 512)            // 512
#define WS_H      (WS_BNB + 512)            // 1024*32
#define WS_RX     (WS_H + BATCH*32)         // 1024*512
#define WS_CA     (WS_RX + BATCH*512)       // 360*16*2
#define WS_FC1T   (WS_CA + N_ANGLES*16*2)   // 360*32
#define WS_UN     (WS_FC1T + N_ANGLES*32)   // 1024*13*16*2

// ================= complex float helpers =================
__device__ __forceinline__ float2 f2(float a, float b){ return make_float2(a,b); }
__device__ __forceinline__ float2 fadd2(float2 a, float2 b){ return f2(a.x+b.x, a.y+b.y); }
__device__ __forceinline__ float2 fsub2(float2 a, float2 b){ return f2(a.x-b.x, a.y-b.y); }
__device__ __forceinline__ float2 fmul2(float2 a, float2 b){ return f2(a.x*b.x - a.y*b.y, a.x*b.y + a.y*b.x); }
__device__ __forceinline__ float2 fconj2(float2 a){ return f2(a.x, -a.y); }
__device__ __forceinline__ float2 fscale2(float2 a, float s){ return f2(a.x*s, a.y*s); }
__device__ __forceinline__ float  fabs2sq(float2 a){ return a.x*a.x + a.y*a.y; }
__device__ __forceinline__ float2 fmad2(float2 b, float2 c, float2 a){ return fadd2(a, fmul2(b,c)); }
__device__ __forceinline__ float2 fdivc2(float2 a, float2 b){
  float id = __frcp_rn(b.x*b.x + b.y*b.y);
  return f2((a.x*b.x + a.y*b.y)*id, (a.y*b.x - a.x*b.y)*id);
}
__device__ __forceinline__ float2 csqrtf2(float2 z){
  float m = __fsqrt_rn(z.x*z.x + z.y*z.y);
  if (m == 0.f) return f2(0.f, 0.f);
  float u = __fsqrt_rn(0.5f*(m + fabsf(z.x)));
  if (z.x >= 0.f) return f2(u, z.y/(2.f*u));
  float v = (z.y >= 0.f) ? u : -u;
  return f2(z.y/(2.f*v), v);
}
__device__ __forceinline__ float2 shfl2(float2 v, int src){
  return f2(__shfl(v.x, src, 64), __shfl(v.y, src, 64));
}

// ================= prep: conj(A) table + fc1 transpose =================
__global__ void prep_kernel(const float* __restrict__ fc1W, float* __restrict__ CA,
                            float* __restrict__ fc1T){
  int i = blockIdx.x*256 + threadIdx.x;
  if (i < N_ANGLES*16){
    int a = i >> 4, n = i & 15;
    float ang = (float)(-PI_D*0.5 + (double)a * (PI_D/359.0));
    float ph = (float)PI_D * (float)n * sinf(ang);
    CA[2*i]   = cosf(ph);   // conj(A) = cos + i sin
    CA[2*i+1] = sinf(ph);
  }
  if (i < N_ANGLES*32){
    int a = i >> 5, j = i & 31;
    fc1T[i] = fc1W[j*N_ANGLES + a];   // fc1T[a][j]
  }
}

// ================= batchnorm stats over (B, C) per t' =================
__global__ __launch_bounds__(256) void bn_stats_kernel(
    const float* __restrict__ Xr, const float* __restrict__ Xi,
    const float* __restrict__ bnw, const float* __restrict__ bnb,
    float* __restrict__ bnA, float* __restrict__ bnB){
  const int tp = blockIdx.x;                 // feature t' in [0,512)
  const int n = tp >> 4;
  const float* src = (n < 16) ? Xr : Xi;
  const size_t roff = (size_t)(n & 15)*512 + (size_t)(tp & 15)*32;
  const int c4 = threadIdx.x & 7;            // float4 index within the 32-float run
  const int bg = threadIdx.x >> 3;           // 0..31
  double s = 0.0, ss = 0.0;
  for (int i = 0; i < 32; i++){
    int b = bg*32 + i;
    const float4 v = *(const float4*)(src + (size_t)b*8192 + roff + c4*4);
    s  += (double)v.x + (double)v.y + (double)v.z + (double)v.w;
    ss += (double)v.x*v.x + (double)v.y*v.y + (double)v.z*v.z + (double)v.w*v.w;
  }
  for (int m=1; m<64; m<<=1){ s += __shfl_xor(s, m, 64); ss += __shfl_xor(ss, m, 64); }
  __shared__ double sh[4][2];
  int wid = threadIdx.x >> 6, lane = threadIdx.x & 63;
  if (lane == 0){ sh[wid][0] = s; sh[wid][1] = ss; }
  __syncthreads();
  if (threadIdx.x == 0){
    double S  = sh[0][0]+sh[1][0]+sh[2][0]+sh[3][0];
    double SS = sh[0][1]+sh[1][1]+sh[2][1]+sh[3][1];
    double mean = S/32768.0;
    double var  = SS/32768.0 - mean*mean;
    double inv  = 1.0/sqrt(var + 1e-5);
    double a = (double)bnw[tp]*inv;
    bnA[tp] = (float)a;
    bnB[tp] = (float)((double)bnb[tp] - mean*a);
  }
}

// ================= fused BN-apply + GRU (64 lanes per batch elem) =================
// BN pre-applied at LDS staging. rcp-based gates. h via wave-private LDS broadcast.
__global__ __launch_bounds__(256) void gru_kernel(
    const float* __restrict__ Xr, const float* __restrict__ Xi,
    const float* __restrict__ Wih, const float* __restrict__ Whh,
    const float* __restrict__ bih, const float* __restrict__ bhh,
    const float* __restrict__ bnA, const float* __restrict__ bnB,
    float* __restrict__ hbuf){
  const int lane = threadIdx.x & 63;
  const int wv   = threadIdx.x >> 6;
  const int b    = blockIdx.x*4 + wv;
  const int j    = lane & 31;      // output index
  const int k0   = (lane >> 5)*16; // this lane's k-half
  const int tt0  = lane >> 3;      // 0..7 : step-within-chunk of first float4
  __shared__ float xb[4][2][512];
  __shared__ float hl[4][32];

  float WI0[16], WI1[16], WI2[16], WH0[16], WH1[16], WH2[16];
  #pragma unroll
  for (int kk=0; kk<16; kk++){
    WI0[kk] = Wih[(j     )*32 + k0+kk];
    WI1[kk] = Wih[(32+j  )*32 + k0+kk];
    WI2[kk] = Wih[(64+j  )*32 + k0+kk];
    WH0[kk] = Whh[(j     )*32 + k0+kk];
    WH1[kk] = Whh[(32+j  )*32 + k0+kk];
    WH2[kk] = Whh[(64+j  )*32 + k0+kk];
  }
  const float br  = bih[j]    + bhh[j];
  const float bz  = bih[32+j] + bhh[32+j];
  const float bin = bih[64+j];
  const float bhn = bhh[64+j];
  const size_t xbase = (size_t)b*8192;

  // prologue: chunk 0 = Xr row 0, BN applied at store
  {
    const float* s0 = Xr + xbase;
    float4 p0 = *(const float4*)(s0 + lane*4);
    float4 p1 = *(const float4*)(s0 + 256 + lane*4);
    const float a0 = bnA[tt0],   b0 = bnB[tt0];
    const float a1 = bnA[8+tt0], b1 = bnB[8+tt0];
    p0.x = fmaf(p0.x,a0,b0); p0.y = fmaf(p0.y,a0,b0); p0.z = fmaf(p0.z,a0,b0); p0.w = fmaf(p0.w,a0,b0);
    p1.x = fmaf(p1.x,a1,b1); p1.y = fmaf(p1.y,a1,b1); p1.z = fmaf(p1.z,a1,b1); p1.w = fmaf(p1.w,a1,b1);
    *(float4*)&xb[wv][0][lane*4]       = p0;
    *(float4*)&xb[wv][0][256 + lane*4] = p1;
  }
  hl[wv][j] = 0.f;   // lanes j and j+32 write same value: benign
  float h = 0.f;

  for (int m=0; m<32; m++){
    float4 q0, q1; float a0n=0.f,b0n=0.f,a1n=0.f,b1n=0.f;
    if (m < 31){
      const int mm = m+1;
      const float* s2 = ((mm < 16) ? Xr : Xi) + xbase + (size_t)(mm & 15)*512;
      q0 = *(const float4*)(s2 + lane*4);
      q1 = *(const float4*)(s2 + 256 + lane*4);
      a0n = bnA[mm*16+tt0];   b0n = bnB[mm*16+tt0];
      a1n = bnA[mm*16+8+tt0]; b1n = bnB[mm*16+8+tt0];
    }
    const float* xc = xb[wv][m & 1];
    for (int tt=0; tt<16; tt++){
      // h broadcast read first (long-latency op on the recurrent chain)
      const float4 ha = *(const float4*)&hl[wv][k0];
      const float4 hb = *(const float4*)&hl[wv][k0 + 4];
      const float4 hc = *(const float4*)&hl[wv][k0 + 8];
      const float4 hd = *(const float4*)&hl[wv][k0 + 12];
      // x-dots (independent of h -> fills LDS latency)
      const float4 xa = *(const float4*)&xc[tt*32 + k0];
      const float4 xb2= *(const float4*)&xc[tt*32 + k0 + 4];
      const float4 xc2= *(const float4*)&xc[tt*32 + k0 + 8];
      const float4 xd = *(const float4*)&xc[tt*32 + k0 + 12];
      float xr16[16] = {xa.x,xa.y,xa.z,xa.w, xb2.x,xb2.y,xb2.z,xb2.w,
                        xc2.x,xc2.y,xc2.z,xc2.w, xd.x,xd.y,xd.z,xd.w};
      float gxr=0.f, gxz=0.f, gxn=0.f;
      #pragma unroll
      for (int kk=0; kk<16; kk++){
        gxr = fmaf(xr16[kk], WI0[kk], gxr);
        gxz = fmaf(xr16[kk], WI1[kk], gxz);
        gxn = fmaf(xr16[kk], WI2[kk], gxn);
      }
      float hr16[16] = {ha.x,ha.y,ha.z,ha.w, hb.x,hb.y,hb.z,hb.w,
                        hc.x,hc.y,hc.z,hc.w, hd.x,hd.y,hd.z,hd.w};
      float ghr=0.f, ghz=0.f, ghn=0.f;
      #pragma unroll
      for (int kk=0; kk<16; kk++){
        ghr = fmaf(hr16[kk], WH0[kk], ghr);
        ghz = fmaf(hr16[kk], WH1[kk], ghz);
        ghn = fmaf(hr16[kk], WH2[kk], ghn);
      }
      float grt = gxr + ghr;
      float gzt = gxz + ghz;
      grt += __shfl_xor(grt, 32, 64);
      gzt += __shfl_xor(gzt, 32, 64);
      float gnx = gxn + __shfl_xor(gxn, 32, 64);
      float hnv = ghn + __shfl_xor(ghn, 32, 64);
      const float r = __frcp_rn(1.0f + __expf(-(grt + br)));
      const float z = __frcp_rn(1.0f + __expf(-(gzt + bz)));
      const float nn = gnx + bin + r*(hnv + bhn);
      const float th = 1.0f - 2.0f*__frcp_rn(1.0f + __expf(2.0f*nn));  // tanh
      h = th + z*(h - th);
      hl[wv][j] = h;   // both halves write identical value
    }
    if (m < 31){
      q0.x = fmaf(q0.x,a0n,b0n); q0.y = fmaf(q0.y,a0n,b0n); q0.z = fmaf(q0.z,a0n,b0n); q0.w = fmaf(q0.w,a0n,b0n);
      q1.x = fmaf(q1.x,a1n,b1n); q1.y = fmaf(q1.y,a1n,b1n); q1.z = fmaf(q1.z,a1n,b1n); q1.w = fmaf(q1.w,a1n,b1n);
      *(float4*)&xb[wv][(m+1)&1][lane*4]       = q0;
      *(float4*)&xb[wv][(m+1)&1][256 + lane*4] = q1;
    }
  }
  if (lane < 32) hbuf[(size_t)b*32 + j] = h;
}

// ================= h -> Rx (K matrix entries) =================
__global__ __launch_bounds__(256) void rx_kernel(
    const float* __restrict__ hbuf, const float* __restrict__ fcW,
    const float* __restrict__ fcb, float* __restrict__ Rx){
  const int b = blockIdx.x;
  __shared__ float hs[32];
  if (threadIdx.x < 32) hs[threadIdx.x] = hbuf[(size_t)b*32 + threadIdx.x];
  __syncthreads();
  for (int o = threadIdx.x; o < 512; o += 256){
    float acc = fcb[o];
    const float4* W4 = (const float4*)(fcW + o*32);
    const float4* H4 = (const float4*)hs;
    #pragma unroll
    for (int q=0; q<8; q++){
      const float4 w = W4[q], hh = H4[q];
      acc += w.x*hh.x + w.y*hh.y + w.z*hh.z + w.w*hh.w;
    }
    Rx[(size_t)b*512 + o] = acc;
  }
}

// ================= complex 16x16 eig, fp32, one wave per matrix ================
// Single-wave block: LDS ops complete in program order across the wave -> no
// __syncthreads needed; wave_barrier() is a free compiler scheduling fence.
#define LD 17
__global__ __launch_bounds__(64) void eig_kernel(
    const float* __restrict__ Rx, float* __restrict__ Un){
  __shared__ float2 T[16*LD];
  __shared__ float2 Q[16*LD];
  __shared__ float2 Y[16*LD];
  __shared__ float2 ev[16];
  const int lane = threadIdx.x;
  const int b = blockIdx.x;
  const float* rx = Rx + (size_t)b*512;

  float hn2;
  {
    const float4 re = *(const float4*)(rx + lane*4);
    const float4 im = *(const float4*)(rx + 256 + lane*4);
    const float rr[4] = {re.x, re.y, re.z, re.w};
    const float ii[4] = {im.x, im.y, im.z, im.w};
    #pragma unroll
    for (int q=0; q<4; q++){
      const int e = lane*4 + q;
      const int r = e >> 4, c = e & 15;
      T[r*LD+c] = f2(rr[q], ii[q]);
      Q[r*LD+c] = f2((r==c)?1.f:0.f, 0.f);
    }
    float hp = rr[0]*rr[0]+rr[1]*rr[1]+rr[2]*rr[2]+rr[3]*rr[3]
             + ii[0]*ii[0]+ii[1]*ii[1]+ii[2]*ii[2]+ii[3]*ii[3];
    for (int m=1; m<64; m<<=1) hp += __shfl_xor(hp, m, 64);
    hn2 = (hp == 0.f) ? 1.f : hp;
  }
  __builtin_amdgcn_wave_barrier();

  // ---- Householder Hessenberg, accumulating Q ----
  for (int k=0; k<14; k++){
    float2 xr = f2(0.f,0.f);
    if (lane >= k+1 && lane < 16) xr = T[lane*LD+k];
    float nx2 = fabs2sq(xr);
    nx2 += __shfl_xor(nx2, 1, 64);
    nx2 += __shfl_xor(nx2, 2, 64);
    nx2 += __shfl_xor(nx2, 4, 64);
    nx2 += __shfl_xor(nx2, 8, 64);
    nx2 = __shfl(nx2, lane & 15, 64);   // broadcast group sum
    if (nx2 > 1e-30f){
      const float2 alpha = T[(k+1)*LD+k];
      const float anorm = __fsqrt_rn(fabs2sq(alpha));
      const float normx = __fsqrt_rn(nx2);
      const float2 beta = (anorm > 0.f) ? fscale2(alpha, -normx/anorm) : f2(-normx, 0.f);
      const float vn2 = 2.f*nx2 + 2.f*normx*anorm;
      const float inv = __frsqrt_rn(vn2);
      float2 wvl = fscale2(xr, inv);
      if (lane == k+1) wvl = fscale2(fsub2(xr, beta), inv);
      if (lane < 16) ev[lane] = (lane >= k+1) ? wvl : f2(0.f,0.f);
      __builtin_amdgcn_wave_barrier();
      if (lane < 16){   // left: column j = lane
        float2 d = f2(0.f,0.f);
        for (int r=k+1; r<16; r++) d = fmad2(fconj2(ev[r]), T[r*LD+lane], d);
        d = fscale2(d, 2.f);
        for (int r=k+1; r<16; r++) T[r*LD+lane] = fsub2(T[r*LD+lane], fmul2(ev[r], d));
      }
      __builtin_amdgcn_wave_barrier();
      if (lane < 32){   // right: rows of T (lanes 0-15) and Q (lanes 16-31)
        const int r0 = lane & 15;
        float2* M = (lane < 16) ? T : Q;
        float2 d = f2(0.f,0.f);
        for (int r=k+1; r<16; r++) d = fmad2(M[r0*LD+r], ev[r], d);
        d = fscale2(d, 2.f);
        for (int r=k+1; r<16; r++) M[r0*LD+r] = fsub2(M[r0*LD+r], fmul2(d, fconj2(ev[r])));
      }
      __builtin_amdgcn_wave_barrier();
    }
  }

  // ---- shifted QR: ballot deflation scan + R3-style rotation body ----
  unsigned long long deflmask = 0ull;
  int hi = 15, its = 0;
  const float eps2f = 1e-10f;    // (|sd|/|sc|)^2 threshold ~ (1e-5)^2
  for (int tot=0; tot<150; tot++){
    float2 sub = f2(0.f,0.f), dd0 = f2(0.f,0.f), dd1 = f2(0.f,0.f), sup = f2(0.f,0.f);
    if (lane >= 1 && lane < 16){
      sub = T[lane*LD+lane-1];
      dd0 = T[(lane-1)*LD+(lane-1)];
      dd1 = T[lane*LD+lane];
      sup = T[(lane-1)*LD+lane];
    }
    float sc2 = fabs2sq(dd0) + fabs2sq(dd1);
    if (sc2 == 0.f) sc2 = hn2;
    const bool fdef = (lane >= 1 && lane < 16) && (fabs2sq(sub) <= eps2f*sc2);
    deflmask |= __ballot(fdef);
    while (hi > 0 && ((deflmask >> hi) & 1ull)){ hi--; its = 0; }
    if (hi <= 0) break;
    const unsigned long long m2 = deflmask & ((1ull << hi) - 1ull);
    const int lo = m2 ? (63 - __builtin_clzll(m2)) : 0;
    its++;
    // window corners gathered from scan registers (no extra LDS reads)
    const float2 aa = shfl2(dd0, hi);
    const float2 bb = shfl2(sup, hi);
    const float2 cc = shfl2(sub, hi);
    const float2 dd = shfl2(dd1, hi);
    float2 mu;
    if (its % 6 == 0){
      mu = f2(dd.x + 0.75f*__fsqrt_rn(fabs2sq(cc)), dd.y);   // exceptional
    } else {
      const float2 t2 = fscale2(fsub2(aa, dd), 0.5f);
      const float2 bc = fmul2(bb, cc);
      const float2 del = csqrtf2(fadd2(fmul2(t2, t2), bc));
      const float2 d1 = fadd2(t2, del), d2v = fsub2(t2, del);
      const float2 den = (fabs2sq(d1) >= fabs2sq(d2v)) ? d1 : d2v;
      mu = (fabs2sq(den) > 0.f) ? fsub2(dd, fdivc2(bc, den)) : dd;
    }
    float2 x = fsub2(shfl2(dd0, lo+1), mu);
    float2 y = shfl2(sub, lo+1);
    for (int i=lo; i<hi; i++){
      // rotation params (all lanes, redundant)
      const float ax2 = fabs2sq(x), ay2 = fabs2sq(y);
      float c_; float2 s;
      if (ax2 < 1e-30f){
        if (ay2 < 1e-37f){ c_ = 1.f; s = f2(0.f,0.f); }
        else { c_ = 0.f; s = fscale2(fconj2(y), __frsqrt_rn(ay2)); }
      } else {
        const float inv_ax = __frsqrt_rn(ax2);
        const float inv_rr = __frsqrt_rn(ax2 + ay2);
        c_ = ax2*inv_ax*inv_rr;   // = |x| / r
        s = fscale2(fmul2(x, fconj2(y)), inv_ax*inv_rr);
      }
      // role partition: 0 = row-update, 1 = T col-update, 2 = Q col-update,
      // 3 (lanes 48-51) = 2x2 intersection
      const int q16 = lane & 15;
      const int role = lane >> 4;
      float2* Mp = (role == 2) ? Q : T;
      int ia = 0, ib = 0; bool active = false;
      if (role == 0){ ia = i*LD+q16; ib = (i+1)*LD+q16; active = (q16!=i)&&(q16!=i+1); }
      else if (role == 1){ ia = q16*LD+i; ib = ia+1; active = (q16!=i)&&(q16!=i+1); }
      else if (role == 2){ ia = q16*LD+i; ib = ia+1; active = true; }
      if (active){
        const float2 A = Mp[ia], B = Mp[ib];
        const float2 sl = (role == 0) ? s : fconj2(s);
        Mp[ia] = fadd2(fscale2(A, c_), fmul2(sl, B));
        Mp[ib] = fsub2(fscale2(B, c_), fmul2(fconj2(sl), A));
      }
      if (role == 3 && q16 < 4){   // 4 lanes: broadcast-read 2x2, each writes one entry
        const float2 t00 = T[i*LD+i],     t01 = T[i*LD+i+1];
        const float2 t10 = T[(i+1)*LD+i], t11 = T[(i+1)*LD+i+1];
        const float2 r0c0 = fadd2(fscale2(t00, c_), fmul2(s, t10));
        const float2 r0c1 = fadd2(fscale2(t01, c_), fmul2(s, t11));
        const float2 r1c0 = fsub2(fscale2(t10, c_), fmul2(fconj2(s), t00));
        const float2 r1c1 = fsub2(fscale2(t11, c_), fmul2(fconj2(s), t01));
        float2 outv;
        if (q16 == 0)      outv = fadd2(fscale2(r0c0, c_), fmul2(fconj2(s), r0c1));
        else if (q16 == 1) outv = fsub2(fscale2(r0c1, c_), fmul2(s, r0c0));
        else if (q16 == 2) outv = fadd2(fscale2(r1c0, c_), fmul2(fconj2(s), r1c1));
        else               outv = fsub2(fscale2(r1c1, c_), fmul2(s, r1c0));
        T[(i+(q16>>1))*LD + (i+(q16&1))] = outv;
      }
      __builtin_amdgcn_wave_barrier();
      if (i < hi-1){
        x = T[(i+1)*LD+i];   // in-order LDS read-back (same-wave DS ordering)
        y = T[(i+2)*LD+i];
      }
    }
  }
  __builtin_amdgcn_wave_barrier();

  // ---- eigenvectors: backsolve on triangular T, then V = Q*Y ----
  if (lane < 16) ev[lane] = T[lane*LD+lane];
  __builtin_amdgcn_wave_barrier();
  const float hnf = __fsqrt_rn(hn2);
  const float smin = 1e-6f*hnf + 1e-35f;
  if (lane < 16){
    const int i = lane;
    const float2 lam = ev[i];
    Y[i*LD+i] = f2(1.f, 0.f);
    for (int jj=i-1; jj>=0; jj--){
      float2 sum = f2(0.f,0.f);
      for (int k2=jj+1; k2<=i; k2++) sum = fmad2(T[jj*LD+k2], Y[k2*LD+i], sum);
      float2 den = fsub2(T[jj*LD+jj], lam);
      if (fabs2sq(den) < smin*smin) den = f2(smin, 0.f);
      Y[jj*LD+i] = fdivc2(f2(-sum.x, -sum.y), den);
    }
  }
  __builtin_amdgcn_wave_barrier();
  {
    const int i = lane & 15;       // eigenvector index
    const int g = lane >> 4;       // row-group: rows 4g..4g+3
    float2 v[4]; float nrm = 0.f;
    #pragma unroll
    for (int q=0; q<4; q++){
      const int n = 4*g + q;
      float2 acc = f2(0.f,0.f);
      for (int k2=0; k2<=i; k2++) acc = fmad2(Q[n*LD+k2], Y[k2*LD+i], acc);
      v[q] = acc; nrm += fabs2sq(acc);
    }
    nrm += __shfl_xor(nrm, 16, 64);
    nrm += __shfl_xor(nrm, 32, 64);
    const float inv = __frsqrt_rn(nrm);
    const float mi = fabs2sq(ev[i]);
    int rank = 0;
    for (int k2=0; k2<16; k2++){
      const float mk = fabs2sq(ev[k2]);
      rank += (mk > mi) || (mk == mi && k2 > i);
    }
    if (rank >= 3){
      float* dst = Un + ((size_t)b*NOISE_K + (rank-3))*32 + 8*g;
      float4 w0, w1;
      w0.x = v[0].x*inv; w0.y = v[0].y*inv;
      w0.z = v[1].x*inv; w0.w = v[1].y*inv;
      w1.x = v[2].x*inv; w1.y = v[2].y*inv;
      w1.z = v[3].x*inv; w1.w = v[3].y*inv;
      ((float4*)dst)[0] = w0;
      ((float4*)dst)[1] = w1;
    }
  }
}

// ================= MUSIC spectrum + MLP head =================
__global__ __launch_bounds__(256) void spec_head_kernel(
    const float* __restrict__ Un, const float* __restrict__ CA,
    const float* __restrict__ fc1T, const float* __restrict__ fc1b,
    const float* __restrict__ fc2W, const float* __restrict__ fc2b,
    const float* __restrict__ fc3W, const float* __restrict__ fc3b,
    float* __restrict__ out){
  const int b = blockIdx.x;
  const int tid = threadIdx.x;
  __shared__ float2 Us[NOISE_K*16];
  __shared__ float spec[N_ANGLES];
  __shared__ float y1[32], y2[32];
  if (tid < NOISE_K*16) Us[tid] = ((const float2*)Un)[(size_t)b*NOISE_K*16 + tid];
  __syncthreads();
  for (int a = tid; a < N_ANGLES; a += 256){
    float sr[NOISE_K], si[NOISE_K];
    #pragma unroll
    for (int k=0; k<NOISE_K; k++){ sr[k]=0.f; si[k]=0.f; }
    for (int n=0; n<16; n++){
      float2 ca = ((const float2*)CA)[a*16+n];
      #pragma unroll
      for (int k=0; k<NOISE_K; k++){
        float2 u = Us[k*16+n];
        sr[k] += ca.x*u.x - ca.y*u.y;
        si[k] += ca.x*u.y + ca.y*u.x;
      }
    }
    float d = 0.f;
    #pragma unroll
    for (int k=0; k<NOISE_K; k++) d += sr[k]*sr[k] + si[k]*si[k];
    spec[a] = 1.0f/d;
  }
  __syncthreads();
  if (tid < 32){
    float acc = fc1b[tid];
    for (int a=0; a<N_ANGLES; a++) acc += spec[a]*fc1T[a*32+tid];
    y1[tid] = fmaxf(acc, 0.f);
  }
  __syncthreads();
  if (tid < 32){
    float acc = fc2b[tid];
    #pragma unroll
    for (int k=0; k<32; k++) acc += y1[k]*fc2W[tid*32+k];
    y2[tid] = fmaxf(acc, 0.f);
  }
  __syncthreads();
  if (tid < 32){
    float acc = fc2b[tid];
    #pragma unroll
    for (int k=0; k<32; k++) acc += y2[k]*fc2W[tid*32+k];
    y1[tid] = fmaxf(acc, 0.f);
  }
  __syncthreads();
  if (tid < 3){
    float acc = fc3b[tid];
    #pragma unroll
    for (int k=0; k<32; k++) acc += y1[k]*fc3W[tid*32+k];
    out[(size_t)b*3 + tid] = acc;
  }
}

// ================= launcher =================
extern "C" void kernel_launch(void* const* d_in, const int* in_sizes, int n_in,
                              void* d_out, int out_size, void* d_ws, size_t ws_size,
                              hipStream_t stream){
  (void)in_sizes; (void)n_in; (void)out_size; (void)ws_size;
  const float* Xr   = (const float*)d_in[0];
  const float* Xi   = (const float*)d_in[1];
  const float* bnw  = (const float*)d_in[2];
  const float* bnb  = (const float*)d_in[3];
  const float* Wih  = (const float*)d_in[4];
  const float* Whh  = (const float*)d_in[5];
  const float* bih  = (const float*)d_in[6];
  const float* bhh  = (const float*)d_in[7];
  const float* fcW  = (const float*)d_in[8];
  const float* fcb  = (const float*)d_in[9];
  const float* fc1W = (const float*)d_in[10];
  const float* fc1b = (const float*)d_in[11];
  const float* fc2W = (const float*)d_in[12];
  const float* fc2b = (const float*)d_in[13];
  const float* fc3W = (const float*)d_in[14];
  const float* fc3b = (const float*)d_in[15];

  float* ws   = (float*)d_ws;
  float* bnA  = ws + WS_BNA;
  float* bnB  = ws + WS_BNB;
  float* hbuf = ws + WS_H;
  float* RxB  = ws + WS_RX;
  float* CA   = ws + WS_CA;
  float* fc1T = ws + WS_FC1T;
  float* UnB  = ws + WS_UN;

  hipLaunchKernelGGL(prep_kernel, dim3(45), dim3(256), 0, stream, fc1W, CA, fc1T);
  hipLaunchKernelGGL(bn_stats_kernel, dim3(512), dim3(256), 0, stream,
                     Xr, Xi, bnw, bnb, bnA, bnB);
  hipLaunchKernelGGL(gru_kernel, dim3(256), dim3(256), 0, stream,
                     Xr, Xi, Wih, Whh, bih, bhh, bnA, bnB, hbuf);
  hipLaunchKernelGGL(rx_kernel, dim3(1024), dim3(256), 0, stream,
                     hbuf, fcW, fcb, RxB);
  hipLaunchKernelGGL(eig_kernel, dim3(1024), dim3(64), 0, stream, RxB, UnB);
  hipLaunchKernelGGL(spec_head_kernel, dim3(1024), dim3(256), 0, stream,
                     UnB, CA, fc1T, fc1b, fc2W, fc2b, fc3W, fc3b, (float*)d_out);
}

// Round 6
// 894.004 us; speedup vs baseline: 1.3013x; 1.0451x over previous
//
#include <hip/hip_runtime.h>

#define PI_D 3.14159265358979323846
#define BATCH 1024
#define NOISE_K 13
#define N_ANGLES 360

// ---------------- ws layout (float offsets) ----------------
#define WS_BNA    0                         // 512
#define WS_BNB    (WS_BNA + 512)            // 512
#define WS_H      (WS_BNB + 512)            // 1024*32
#define WS_RX     (WS_H + BATCH*32)         // 1024*512
#define WS_CA     (WS_RX + BATCH*512)       // 360*16*2
#define WS_FC1T   (WS_CA + N_ANGLES*16*2)   // 360*32
#define WS_UN     (WS_FC1T + N_ANGLES*32)   // 1024*13*16*2

// ================= complex float helpers =================
__device__ __forceinline__ float2 f2(float a, float b){ return make_float2(a,b); }
__device__ __forceinline__ float2 fadd2(float2 a, float2 b){ return f2(a.x+b.x, a.y+b.y); }
__device__ __forceinline__ float2 fsub2(float2 a, float2 b){ return f2(a.x-b.x, a.y-b.y); }
__device__ __forceinline__ float2 fmul2(float2 a, float2 b){ return f2(a.x*b.x - a.y*b.y, a.x*b.y + a.y*b.x); }
__device__ __forceinline__ float2 fconj2(float2 a){ return f2(a.x, -a.y); }
__device__ __forceinline__ float2 fscale2(float2 a, float s){ return f2(a.x*s, a.y*s); }
__device__ __forceinline__ float  fabs2sq(float2 a){ return a.x*a.x + a.y*a.y; }
__device__ __forceinline__ float2 fmad2(float2 b, float2 c, float2 a){ return fadd2(a, fmul2(b,c)); }
__device__ __forceinline__ float2 fdivc2(float2 a, float2 b){
  float id = __frcp_rn(b.x*b.x + b.y*b.y);
  return f2((a.x*b.x + a.y*b.y)*id, (a.y*b.x - a.x*b.y)*id);
}
__device__ __forceinline__ float2 csqrtf2(float2 z){
  float m = __fsqrt_rn(z.x*z.x + z.y*z.y);
  if (m == 0.f) return f2(0.f, 0.f);
  float u = __fsqrt_rn(0.5f*(m + fabsf(z.x)));
  if (z.x >= 0.f) return f2(u, z.y/(2.f*u));
  float v = (z.y >= 0.f) ? u : -u;
  return f2(z.y/(2.f*v), v);
}

// ================= prep: conj(A) table + fc1 transpose =================
__global__ void prep_kernel(const float* __restrict__ fc1W, float* __restrict__ CA,
                            float* __restrict__ fc1T){
  int i = blockIdx.x*256 + threadIdx.x;
  if (i < N_ANGLES*16){
    int a = i >> 4, n = i & 15;
    float ang = (float)(-PI_D*0.5 + (double)a * (PI_D/359.0));
    float ph = (float)PI_D * (float)n * sinf(ang);
    CA[2*i]   = cosf(ph);   // conj(A) = cos + i sin
    CA[2*i+1] = sinf(ph);
  }
  if (i < N_ANGLES*32){
    int a = i >> 5, j = i & 31;
    fc1T[i] = fc1W[j*N_ANGLES + a];   // fc1T[a][j]
  }
}

// ================= batchnorm stats over (B, C) per t' =================
__global__ __launch_bounds__(256) void bn_stats_kernel(
    const float* __restrict__ Xr, const float* __restrict__ Xi,
    const float* __restrict__ bnw, const float* __restrict__ bnb,
    float* __restrict__ bnA, float* __restrict__ bnB){
  const int tp = blockIdx.x;                 // feature t' in [0,512)
  const int n = tp >> 4;
  const float* src = (n < 16) ? Xr : Xi;
  const size_t roff = (size_t)(n & 15)*512 + (size_t)(tp & 15)*32;
  const int c4 = threadIdx.x & 7;            // float4 index within the 32-float run
  const int bg = threadIdx.x >> 3;           // 0..31
  double s = 0.0, ss = 0.0;
  for (int i = 0; i < 32; i++){
    int b = bg*32 + i;
    const float4 v = *(const float4*)(src + (size_t)b*8192 + roff + c4*4);
    s  += (double)v.x + (double)v.y + (double)v.z + (double)v.w;
    ss += (double)v.x*v.x + (double)v.y*v.y + (double)v.z*v.z + (double)v.w*v.w;
  }
  for (int m=1; m<64; m<<=1){ s += __shfl_xor(s, m, 64); ss += __shfl_xor(ss, m, 64); }
  __shared__ double sh[4][2];
  int wid = threadIdx.x >> 6, lane = threadIdx.x & 63;
  if (lane == 0){ sh[wid][0] = s; sh[wid][1] = ss; }
  __syncthreads();
  if (threadIdx.x == 0){
    double S  = sh[0][0]+sh[1][0]+sh[2][0]+sh[3][0];
    double SS = sh[0][1]+sh[1][1]+sh[2][1]+sh[3][1];
    double mean = S/32768.0;
    double var  = SS/32768.0 - mean*mean;
    double inv  = 1.0/sqrt(var + 1e-5);
    double a = (double)bnw[tp]*inv;
    bnA[tp] = (float)a;
    bnB[tp] = (float)((double)bnb[tp] - mean*a);
  }
}

// ================= fused BN-apply + GRU (64 lanes per batch elem) =================
// BN pre-applied at LDS staging. rcp-based gates. h via wave-private LDS broadcast.
__global__ __launch_bounds__(256) void gru_kernel(
    const float* __restrict__ Xr, const float* __restrict__ Xi,
    const float* __restrict__ Wih, const float* __restrict__ Whh,
    const float* __restrict__ bih, const float* __restrict__ bhh,
    const float* __restrict__ bnA, const float* __restrict__ bnB,
    float* __restrict__ hbuf){
  const int lane = threadIdx.x & 63;
  const int wv   = threadIdx.x >> 6;
  const int b    = blockIdx.x*4 + wv;
  const int j    = lane & 31;      // output index
  const int k0   = (lane >> 5)*16; // this lane's k-half
  const int tt0  = lane >> 3;      // 0..7 : step-within-chunk of first float4
  __shared__ float xb[4][2][512];
  __shared__ float hl[4][32];

  float WI0[16], WI1[16], WI2[16], WH0[16], WH1[16], WH2[16];
  #pragma unroll
  for (int kk=0; kk<16; kk++){
    WI0[kk] = Wih[(j     )*32 + k0+kk];
    WI1[kk] = Wih[(32+j  )*32 + k0+kk];
    WI2[kk] = Wih[(64+j  )*32 + k0+kk];
    WH0[kk] = Whh[(j     )*32 + k0+kk];
    WH1[kk] = Whh[(32+j  )*32 + k0+kk];
    WH2[kk] = Whh[(64+j  )*32 + k0+kk];
  }
  const float br  = bih[j]    + bhh[j];
  const float bz  = bih[32+j] + bhh[32+j];
  const float bin = bih[64+j];
  const float bhn = bhh[64+j];
  const size_t xbase = (size_t)b*8192;

  // prologue: chunk 0 = Xr row 0, BN applied at store
  {
    const float* s0 = Xr + xbase;
    float4 p0 = *(const float4*)(s0 + lane*4);
    float4 p1 = *(const float4*)(s0 + 256 + lane*4);
    const float a0 = bnA[tt0],   b0 = bnB[tt0];
    const float a1 = bnA[8+tt0], b1 = bnB[8+tt0];
    p0.x = fmaf(p0.x,a0,b0); p0.y = fmaf(p0.y,a0,b0); p0.z = fmaf(p0.z,a0,b0); p0.w = fmaf(p0.w,a0,b0);
    p1.x = fmaf(p1.x,a1,b1); p1.y = fmaf(p1.y,a1,b1); p1.z = fmaf(p1.z,a1,b1); p1.w = fmaf(p1.w,a1,b1);
    *(float4*)&xb[wv][0][lane*4]       = p0;
    *(float4*)&xb[wv][0][256 + lane*4] = p1;
  }
  hl[wv][j] = 0.f;   // lanes j and j+32 write same value: benign
  float h = 0.f;

  for (int m=0; m<32; m++){
    float4 q0, q1; float a0n=0.f,b0n=0.f,a1n=0.f,b1n=0.f;
    if (m < 31){
      const int mm = m+1;
      const float* s2 = ((mm < 16) ? Xr : Xi) + xbase + (size_t)(mm & 15)*512;
      q0 = *(const float4*)(s2 + lane*4);
      q1 = *(const float4*)(s2 + 256 + lane*4);
      a0n = bnA[mm*16+tt0];   b0n = bnB[mm*16+tt0];
      a1n = bnA[mm*16+8+tt0]; b1n = bnB[mm*16+8+tt0];
    }
    const float* xc = xb[wv][m & 1];
    for (int tt=0; tt<16; tt++){
      // h broadcast read first (long-latency op on the recurrent chain)
      const float4 ha = *(const float4*)&hl[wv][k0];
      const float4 hb = *(const float4*)&hl[wv][k0 + 4];
      const float4 hc = *(const float4*)&hl[wv][k0 + 8];
      const float4 hd = *(const float4*)&hl[wv][k0 + 12];
      // x-dots (independent of h -> fills LDS latency)
      const float4 xa = *(const float4*)&xc[tt*32 + k0];
      const float4 xb2= *(const float4*)&xc[tt*32 + k0 + 4];
      const float4 xc2= *(const float4*)&xc[tt*32 + k0 + 8];
      const float4 xd = *(const float4*)&xc[tt*32 + k0 + 12];
      float xr16[16] = {xa.x,xa.y,xa.z,xa.w, xb2.x,xb2.y,xb2.z,xb2.w,
                        xc2.x,xc2.y,xc2.z,xc2.w, xd.x,xd.y,xd.z,xd.w};
      float gxr=0.f, gxz=0.f, gxn=0.f;
      #pragma unroll
      for (int kk=0; kk<16; kk++){
        gxr = fmaf(xr16[kk], WI0[kk], gxr);
        gxz = fmaf(xr16[kk], WI1[kk], gxz);
        gxn = fmaf(xr16[kk], WI2[kk], gxn);
      }
      float hr16[16] = {ha.x,ha.y,ha.z,ha.w, hb.x,hb.y,hb.z,hb.w,
                        hc.x,hc.y,hc.z,hc.w, hd.x,hd.y,hd.z,hd.w};
      float ghr=0.f, ghz=0.f, ghn=0.f;
      #pragma unroll
      for (int kk=0; kk<16; kk++){
        ghr = fmaf(hr16[kk], WH0[kk], ghr);
        ghz = fmaf(hr16[kk], WH1[kk], ghz);
        ghn = fmaf(hr16[kk], WH2[kk], ghn);
      }
      float grt = gxr + ghr;
      float gzt = gxz + ghz;
      grt += __shfl_xor(grt, 32, 64);
      gzt += __shfl_xor(gzt, 32, 64);
      float gnx = gxn + __shfl_xor(gxn, 32, 64);
      float hnv = ghn + __shfl_xor(ghn, 32, 64);
      const float r = __frcp_rn(1.0f + __expf(-(grt + br)));
      const float z = __frcp_rn(1.0f + __expf(-(gzt + bz)));
      const float nn = gnx + bin + r*(hnv + bhn);
      const float th = 1.0f - 2.0f*__frcp_rn(1.0f + __expf(2.0f*nn));  // tanh
      h = th + z*(h - th);
      hl[wv][j] = h;   // both halves write identical value
    }
    if (m < 31){
      q0.x = fmaf(q0.x,a0n,b0n); q0.y = fmaf(q0.y,a0n,b0n); q0.z = fmaf(q0.z,a0n,b0n); q0.w = fmaf(q0.w,a0n,b0n);
      q1.x = fmaf(q1.x,a1n,b1n); q1.y = fmaf(q1.y,a1n,b1n); q1.z = fmaf(q1.z,a1n,b1n); q1.w = fmaf(q1.w,a1n,b1n);
      *(float4*)&xb[wv][(m+1)&1][lane*4]       = q0;
      *(float4*)&xb[wv][(m+1)&1][256 + lane*4] = q1;
    }
  }
  if (lane < 32) hbuf[(size_t)b*32 + j] = h;
}

// ================= h -> Rx (K matrix entries) =================
__global__ __launch_bounds__(256) void rx_kernel(
    const float* __restrict__ hbuf, const float* __restrict__ fcW,
    const float* __restrict__ fcb, float* __restrict__ Rx){
  const int b = blockIdx.x;
  __shared__ float hs[32];
  if (threadIdx.x < 32) hs[threadIdx.x] = hbuf[(size_t)b*32 + threadIdx.x];
  __syncthreads();
  for (int o = threadIdx.x; o < 512; o += 256){
    float acc = fcb[o];
    const float4* W4 = (const float4*)(fcW + o*32);
    const float4* H4 = (const float4*)hs;
    #pragma unroll
    for (int q=0; q<8; q++){
      const float4 w = W4[q], hh = H4[q];
      acc += w.x*hh.x + w.y*hh.y + w.z*hh.z + w.w*hh.w;
    }
    Rx[(size_t)b*512 + o] = acc;
  }
}

// ================= complex 16x16 eig, fp32, one wave per matrix ================
// Single-wave block: LDS ops complete in program order across the wave -> no
// __syncthreads needed; wave_barrier() is a free compiler scheduling fence.
#define LD 17
__global__ __launch_bounds__(64) void eig_kernel(
    const float* __restrict__ Rx, float* __restrict__ Un){
  __shared__ float2 T[16*LD];
  __shared__ float2 Q[16*LD];
  __shared__ float2 Y[16*LD];
  __shared__ float2 ev[16];
  const int lane = threadIdx.x;
  const int b = blockIdx.x;
  const float* rx = Rx + (size_t)b*512;

  float hn2;
  {
    const float4 re = *(const float4*)(rx + lane*4);
    const float4 im = *(const float4*)(rx + 256 + lane*4);
    const float rr[4] = {re.x, re.y, re.z, re.w};
    const float ii[4] = {im.x, im.y, im.z, im.w};
    #pragma unroll
    for (int q=0; q<4; q++){
      const int e = lane*4 + q;
      const int r = e >> 4, c = e & 15;
      T[r*LD+c] = f2(rr[q], ii[q]);
      Q[r*LD+c] = f2((r==c)?1.f:0.f, 0.f);
    }
    float hp = rr[0]*rr[0]+rr[1]*rr[1]+rr[2]*rr[2]+rr[3]*rr[3]
             + ii[0]*ii[0]+ii[1]*ii[1]+ii[2]*ii[2]+ii[3]*ii[3];
    for (int m=1; m<64; m<<=1) hp += __shfl_xor(hp, m, 64);
    hn2 = (hp == 0.f) ? 1.f : hp;
  }
  __builtin_amdgcn_wave_barrier();

  // ---- Householder Hessenberg, accumulating Q ----
  for (int k=0; k<14; k++){
    float2 xr = f2(0.f,0.f);
    if (lane >= k+1 && lane < 16) xr = T[lane*LD+k];
    float nx2 = fabs2sq(xr);
    nx2 += __shfl_xor(nx2, 1, 64);
    nx2 += __shfl_xor(nx2, 2, 64);
    nx2 += __shfl_xor(nx2, 4, 64);
    nx2 += __shfl_xor(nx2, 8, 64);
    nx2 = __shfl(nx2, lane & 15, 64);   // broadcast group sum
    if (nx2 > 1e-30f){
      const float2 alpha = T[(k+1)*LD+k];
      const float anorm = __fsqrt_rn(fabs2sq(alpha));
      const float normx = __fsqrt_rn(nx2);
      const float2 beta = (anorm > 0.f) ? fscale2(alpha, -normx/anorm) : f2(-normx, 0.f);
      const float vn2 = 2.f*nx2 + 2.f*normx*anorm;
      const float inv = __frsqrt_rn(vn2);
      float2 wvl = fscale2(xr, inv);
      if (lane == k+1) wvl = fscale2(fsub2(xr, beta), inv);
      if (lane < 16) ev[lane] = (lane >= k+1) ? wvl : f2(0.f,0.f);
      __builtin_amdgcn_wave_barrier();
      if (lane < 16){   // left: column j = lane
        float2 d = f2(0.f,0.f);
        for (int r=k+1; r<16; r++) d = fmad2(fconj2(ev[r]), T[r*LD+lane], d);
        d = fscale2(d, 2.f);
        for (int r=k+1; r<16; r++) T[r*LD+lane] = fsub2(T[r*LD+lane], fmul2(ev[r], d));
      }
      __builtin_amdgcn_wave_barrier();
      if (lane < 32){   // right: rows of T (lanes 0-15) and Q (lanes 16-31)
        const int r0 = lane & 15;
        float2* M = (lane < 16) ? T : Q;
        float2 d = f2(0.f,0.f);
        for (int r=k+1; r<16; r++) d = fmad2(M[r0*LD+r], ev[r], d);
        d = fscale2(d, 2.f);
        for (int r=k+1; r<16; r++) M[r0*LD+r] = fsub2(M[r0*LD+r], fmul2(d, fconj2(ev[r])));
      }
      __builtin_amdgcn_wave_barrier();
    }
  }

  // ---- shifted QR: ballot deflation scan, broadcast-read corners ----
  unsigned long long deflmask = 0ull;
  int hi = 15, its = 0;
  const float eps2f = 1e-9f;    // (|sd|/|sc|)^2 threshold ~ (3.2e-5)^2
  for (int tot=0; tot<96; tot++){
    float2 sub = f2(0.f,0.f), dd0 = f2(0.f,0.f), dd1 = f2(0.f,0.f);
    if (lane >= 1 && lane < 16){
      sub = T[lane*LD+lane-1];
      dd0 = T[(lane-1)*LD+(lane-1)];
      dd1 = T[lane*LD+lane];
    }
    float sc2 = fabs2sq(dd0) + fabs2sq(dd1);
    if (sc2 == 0.f) sc2 = hn2;
    const bool fdef = (lane >= 1 && lane < 16) && (fabs2sq(sub) <= eps2f*sc2);
    deflmask |= __ballot(fdef);
    while (hi > 0 && ((deflmask >> hi) & 1ull)){ hi--; its = 0; }
    if (hi <= 0) break;
    const unsigned long long m2 = deflmask & ((1ull << hi) - 1ull);
    const int lo = m2 ? (63 - __builtin_clzll(m2)) : 0;
    its++;
    // window corners + shift vector: wave-uniform broadcast LDS reads
    const float2 aa = T[(hi-1)*LD+hi-1];
    const float2 bb = T[(hi-1)*LD+hi];
    const float2 cc = T[hi*LD+hi-1];
    const float2 dd = T[hi*LD+hi];
    const float2 x0 = T[lo*LD+lo];
    const float2 y0 = T[(lo+1)*LD+lo];
    float2 mu;
    if (its % 5 == 0){
      mu = f2(dd.x + 0.75f*__fsqrt_rn(fabs2sq(cc)), dd.y);   // exceptional
    } else {
      const float2 t2 = fscale2(fsub2(aa, dd), 0.5f);
      const float2 bc = fmul2(bb, cc);
      const float2 del = csqrtf2(fadd2(fmul2(t2, t2), bc));
      const float2 d1 = fadd2(t2, del), d2v = fsub2(t2, del);
      const float2 den = (fabs2sq(d1) >= fabs2sq(d2v)) ? d1 : d2v;
      mu = (fabs2sq(den) > 0.f) ? fsub2(dd, fdivc2(bc, den)) : dd;
    }
    float2 x = fsub2(x0, mu);
    float2 y = y0;
    for (int i=lo; i<hi; i++){
      // rotation params (all lanes, redundant)
      const float ax2 = fabs2sq(x), ay2 = fabs2sq(y);
      float c_; float2 s;
      if (ax2 < 1e-30f){
        if (ay2 < 1e-37f){ c_ = 1.f; s = f2(0.f,0.f); }
        else { c_ = 0.f; s = fscale2(fconj2(y), __frsqrt_rn(ay2)); }
      } else {
        const float inv_ax = __frsqrt_rn(ax2);
        const float inv_rr = __frsqrt_rn(ax2 + ay2);
        c_ = ax2*inv_ax*inv_rr;   // = |x| / r
        s = fscale2(fmul2(x, fconj2(y)), inv_ax*inv_rr);
      }
      // role partition: 0 = row-update, 1 = T col-update, 2 = Q col-update,
      // 3 (lanes 48-51) = 2x2 intersection
      const int q16 = lane & 15;
      const int role = lane >> 4;
      float2* Mp = (role == 2) ? Q : T;
      int ia = 0, ib = 0; bool active = false;
      if (role == 0){ ia = i*LD+q16; ib = (i+1)*LD+q16; active = (q16!=i)&&(q16!=i+1); }
      else if (role == 1){ ia = q16*LD+i; ib = ia+1; active = (q16!=i)&&(q16!=i+1); }
      else if (role == 2){ ia = q16*LD+i; ib = ia+1; active = true; }
      if (active){
        const float2 A = Mp[ia], B = Mp[ib];
        const float2 sl = (role == 0) ? s : fconj2(s);
        Mp[ia] = fadd2(fscale2(A, c_), fmul2(sl, B));
        Mp[ib] = fsub2(fscale2(B, c_), fmul2(fconj2(sl), A));
      }
      if (role == 3 && q16 < 4){   // 4 lanes: broadcast-read 2x2, each writes one entry
        const float2 t00 = T[i*LD+i],     t01 = T[i*LD+i+1];
        const float2 t10 = T[(i+1)*LD+i], t11 = T[(i+1)*LD+i+1];
        const float2 r0c0 = fadd2(fscale2(t00, c_), fmul2(s, t10));
        const float2 r0c1 = fadd2(fscale2(t01, c_), fmul2(s, t11));
        const float2 r1c0 = fsub2(fscale2(t10, c_), fmul2(fconj2(s), t00));
        const float2 r1c1 = fsub2(fscale2(t11, c_), fmul2(fconj2(s), t01));
        float2 outv;
        if (q16 == 0)      outv = fadd2(fscale2(r0c0, c_), fmul2(fconj2(s), r0c1));
        else if (q16 == 1) outv = fsub2(fscale2(r0c1, c_), fmul2(s, r0c0));
        else if (q16 == 2) outv = fadd2(fscale2(r1c0, c_), fmul2(fconj2(s), r1c1));
        else               outv = fsub2(fscale2(r1c1, c_), fmul2(s, r1c0));
        T[(i+(q16>>1))*LD + (i+(q16&1))] = outv;
      }
      __builtin_amdgcn_wave_barrier();
      if (i < hi-1){
        x = T[(i+1)*LD+i];   // in-order LDS read-back (same-wave DS ordering)
        y = T[(i+2)*LD+i];
      }
    }
  }
  __builtin_amdgcn_wave_barrier();

  // ---- eigenvectors: backsolve on triangular T, then V = Q*Y ----
  if (lane < 16) ev[lane] = T[lane*LD+lane];
  __builtin_amdgcn_wave_barrier();
  const float hnf = __fsqrt_rn(hn2);
  const float smin = 1e-6f*hnf + 1e-35f;
  if (lane < 16){
    const int i = lane;
    const float2 lam = ev[i];
    Y[i*LD+i] = f2(1.f, 0.f);
    for (int jj=i-1; jj>=0; jj--){
      float2 sum = f2(0.f,0.f);
      for (int k2=jj+1; k2<=i; k2++) sum = fmad2(T[jj*LD+k2], Y[k2*LD+i], sum);
      float2 den = fsub2(T[jj*LD+jj], lam);
      if (fabs2sq(den) < smin*smin) den = f2(smin, 0.f);
      Y[jj*LD+i] = fdivc2(f2(-sum.x, -sum.y), den);
    }
  }
  __builtin_amdgcn_wave_barrier();
  {
    const int i = lane & 15;       // eigenvector index
    const int g = lane >> 4;       // row-group: rows 4g..4g+3
    float2 v[4]; float nrm = 0.f;
    #pragma unroll
    for (int q=0; q<4; q++){
      const int n = 4*g + q;
      float2 acc = f2(0.f,0.f);
      for (int k2=0; k2<=i; k2++) acc = fmad2(Q[n*LD+k2], Y[k2*LD+i], acc);
      v[q] = acc; nrm += fabs2sq(acc);
    }
    nrm += __shfl_xor(nrm, 16, 64);
    nrm += __shfl_xor(nrm, 32, 64);
    const float inv = __frsqrt_rn(nrm);
    const float mi = fabs2sq(ev[i]);
    int rank = 0;
    for (int k2=0; k2<16; k2++){
      const float mk = fabs2sq(ev[k2]);
      rank += (mk > mi) || (mk == mi && k2 > i);
    }
    if (rank >= 3){
      float* dst = Un + ((size_t)b*NOISE_K + (rank-3))*32 + 8*g;
      float4 w0, w1;
      w0.x = v[0].x*inv; w0.y = v[0].y*inv;
      w0.z = v[1].x*inv; w0.w = v[1].y*inv;
      w1.x = v[2].x*inv; w1.y = v[2].y*inv;
      w1.z = v[3].x*inv; w1.w = v[3].y*inv;
      ((float4*)dst)[0] = w0;
      ((float4*)dst)[1] = w1;
    }
  }
}

// ================= MUSIC spectrum + MLP head =================
__global__ __launch_bounds__(256) void spec_head_kernel(
    const float* __restrict__ Un, const float* __restrict__ CA,
    const float* __restrict__ fc1T, const float* __restrict__ fc1b,
    const float* __restrict__ fc2W, const float* __restrict__ fc2b,
    const float* __restrict__ fc3W, const float* __restrict__ fc3b,
    float* __restrict__ out){
  const int b = blockIdx.x;
  const int tid = threadIdx.x;
  __shared__ float2 Us[NOISE_K*16];
  __shared__ float spec[N_ANGLES];
  __shared__ float y1[32], y2[32];
  if (tid < NOISE_K*16) Us[tid] = ((const float2*)Un)[(size_t)b*NOISE_K*16 + tid];
  __syncthreads();
  for (int a = tid; a < N_ANGLES; a += 256){
    float sr[NOISE_K], si[NOISE_K];
    #pragma unroll
    for (int k=0; k<NOISE_K; k++){ sr[k]=0.f; si[k]=0.f; }
    for (int n=0; n<16; n++){
      float2 ca = ((const float2*)CA)[a*16+n];
      #pragma unroll
      for (int k=0; k<NOISE_K; k++){
        float2 u = Us[k*16+n];
        sr[k] += ca.x*u.x - ca.y*u.y;
        si[k] += ca.x*u.y + ca.y*u.x;
      }
    }
    float d = 0.f;
    #pragma unroll
    for (int k=0; k<NOISE_K; k++) d += sr[k]*sr[k] + si[k]*si[k];
    spec[a] = 1.0f/d;
  }
  __syncthreads();
  if (tid < 32){
    float acc = fc1b[tid];
    for (int a=0; a<N_ANGLES; a++) acc += spec[a]*fc1T[a*32+tid];
    y1[tid] = fmaxf(acc, 0.f);
  }
  __syncthreads();
  if (tid < 32){
    float acc = fc2b[tid];
    #pragma unroll
    for (int k=0; k<32; k++) acc += y1[k]*fc2W[tid*32+k];
    y2[tid] = fmaxf(acc, 0.f);
  }
  __syncthreads();
  if (tid < 32){
    float acc = fc2b[tid];
    #pragma unroll
    for (int k=0; k<32; k++) acc += y2[k]*fc2W[tid*32+k];
    y1[tid] = fmaxf(acc, 0.f);
  }
  __syncthreads();
  if (tid < 3){
    float acc = fc3b[tid];
    #pragma unroll
    for (int k=0; k<32; k++) acc += y1[k]*fc3W[tid*32+k];
    out[(size_t)b*3 + tid] = acc;
  }
}

// ================= launcher =================
extern "C" void kernel_launch(void* const* d_in, const int* in_sizes, int n_in,
                              void* d_out, int out_size, void* d_ws, size_t ws_size,
                              hipStream_t stream){
  (void)in_sizes; (void)n_in; (void)out_size; (void)ws_size;
  const float* Xr   = (const float*)d_in[0];
  const float* Xi   = (const float*)d_in[1];
  const float* bnw  = (const float*)d_in[2];
  const float* bnb  = (const float*)d_in[3];
  const float* Wih  = (const float*)d_in[4];
  const float* Whh  = (const float*)d_in[5];
  const float* bih  = (const float*)d_in[6];
  const float* bhh  = (const float*)d_in[7];
  const float* fcW  = (const float*)d_in[8];
  const float* fcb  = (const float*)d_in[9];
  const float* fc1W = (const float*)d_in[10];
  const float* fc1b = (const float*)d_in[11];
  const float* fc2W = (const float*)d_in[12];
  const float* fc2b = (const float*)d_in[13];
  const float* fc3W = (const float*)d_in[14];
  const float* fc3b = (const float*)d_in[15];

  float* ws   = (float*)d_ws;
  float* bnA  = ws + WS_BNA;
  float* bnB  = ws + WS_BNB;
  float* hbuf = ws + WS_H;
  float* RxB  = ws + WS_RX;
  float* CA   = ws + WS_CA;
  float* fc1T = ws + WS_FC1T;
  float* UnB  = ws + WS_UN;

  hipLaunchKernelGGL(prep_kernel, dim3(45), dim3(256), 0, stream, fc1W, CA, fc1T);
  hipLaunchKernelGGL(bn_stats_kernel, dim3(512), dim3(256), 0, stream,
                     Xr, Xi, bnw, bnb, bnA, bnB);
  hipLaunchKernelGGL(gru_kernel, dim3(256), dim3(256), 0, stream,
                     Xr, Xi, Wih, Whh, bih, bhh, bnA, bnB, hbuf);
  hipLaunchKernelGGL(rx_kernel, dim3(1024), dim3(256), 0, stream,
                     hbuf, fcW, fcb, RxB);
  hipLaunchKernelGGL(eig_kernel, dim3(1024), dim3(64), 0, stream, RxB, UnB);
  hipLaunchKernelGGL(spec_head_kernel, dim3(1024), dim3(256), 0, stream,
                     UnB, CA, fc1T, fc1b, fc2W, fc2b, fc3W, fc3b, (float*)d_out);
}

// Round 7
// 879.018 us; speedup vs baseline: 1.3235x; 1.0170x over previous
//
#include <hip/hip_runtime.h>

#define PI_D 3.14159265358979323846
#define BATCH 1024
#define NOISE_K 13
#define N_ANGLES 360

// ---------------- ws layout (float offsets) ----------------
#define WS_BNA    0                         // 512
#define WS_BNB    (WS_BNA + 512)            // 512
#define WS_H      (WS_BNB + 512)            // 1024*32
#define WS_RX     (WS_H + BATCH*32)         // 1024*512
#define WS_CA     (WS_RX + BATCH*512)       // 360*16*2
#define WS_FC1T   (WS_CA + N_ANGLES*16*2)   // 360*32
#define WS_UN     (WS_FC1T + N_ANGLES*32)   // 1024*13*16*2

// ================= complex float helpers =================
__device__ __forceinline__ float2 f2(float a, float b){ return make_float2(a,b); }
__device__ __forceinline__ float2 fadd2(float2 a, float2 b){ return f2(a.x+b.x, a.y+b.y); }
__device__ __forceinline__ float2 fsub2(float2 a, float2 b){ return f2(a.x-b.x, a.y-b.y); }
__device__ __forceinline__ float2 fmul2(float2 a, float2 b){ return f2(a.x*b.x - a.y*b.y, a.x*b.y + a.y*b.x); }
__device__ __forceinline__ float2 fconj2(float2 a){ return f2(a.x, -a.y); }
__device__ __forceinline__ float2 fscale2(float2 a, float s){ return f2(a.x*s, a.y*s); }
__device__ __forceinline__ float  fabs2sq(float2 a){ return a.x*a.x + a.y*a.y; }
__device__ __forceinline__ float2 fmad2(float2 b, float2 c, float2 a){ return fadd2(a, fmul2(b,c)); }
__device__ __forceinline__ float2 fdivc2(float2 a, float2 b){
  float id = __frcp_rn(b.x*b.x + b.y*b.y);
  return f2((a.x*b.x + a.y*b.y)*id, (a.y*b.x - a.x*b.y)*id);
}
__device__ __forceinline__ float2 csqrtf2(float2 z){
  float m = __fsqrt_rn(z.x*z.x + z.y*z.y);
  if (m == 0.f) return f2(0.f, 0.f);
  float u = __fsqrt_rn(0.5f*(m + fabsf(z.x)));
  if (z.x >= 0.f) return f2(u, z.y/(2.f*u));
  float v = (z.y >= 0.f) ? u : -u;
  return f2(z.y/(2.f*v), v);
}

// ================= prep: conj(A) table + fc1 transpose =================
__global__ void prep_kernel(const float* __restrict__ fc1W, float* __restrict__ CA,
                            float* __restrict__ fc1T){
  int i = blockIdx.x*256 + threadIdx.x;
  if (i < N_ANGLES*16){
    int a = i >> 4, n = i & 15;
    float ang = (float)(-PI_D*0.5 + (double)a * (PI_D/359.0));
    float ph = (float)PI_D * (float)n * sinf(ang);
    CA[2*i]   = cosf(ph);   // conj(A) = cos + i sin
    CA[2*i+1] = sinf(ph);
  }
  if (i < N_ANGLES*32){
    int a = i >> 5, j = i & 31;
    fc1T[i] = fc1W[j*N_ANGLES + a];   // fc1T[a][j]
  }
}

// ================= batchnorm stats over (B, C) per t' =================
__global__ __launch_bounds__(256) void bn_stats_kernel(
    const float* __restrict__ Xr, const float* __restrict__ Xi,
    const float* __restrict__ bnw, const float* __restrict__ bnb,
    float* __restrict__ bnA, float* __restrict__ bnB){
  const int tp = blockIdx.x;                 // feature t' in [0,512)
  const int n = tp >> 4;
  const float* src = (n < 16) ? Xr : Xi;
  const size_t roff = (size_t)(n & 15)*512 + (size_t)(tp & 15)*32;
  const int c4 = threadIdx.x & 7;            // float4 index within the 32-float run
  const int bg = threadIdx.x >> 3;           // 0..31
  double s = 0.0, ss = 0.0;
  for (int i = 0; i < 32; i++){
    int b = bg*32 + i;
    const float4 v = *(const float4*)(src + (size_t)b*8192 + roff + c4*4);
    s  += (double)v.x + (double)v.y + (double)v.z + (double)v.w;
    ss += (double)v.x*v.x + (double)v.y*v.y + (double)v.z*v.z + (double)v.w*v.w;
  }
  for (int m=1; m<64; m<<=1){ s += __shfl_xor(s, m, 64); ss += __shfl_xor(ss, m, 64); }
  __shared__ double sh[4][2];
  int wid = threadIdx.x >> 6, lane = threadIdx.x & 63;
  if (lane == 0){ sh[wid][0] = s; sh[wid][1] = ss; }
  __syncthreads();
  if (threadIdx.x == 0){
    double S  = sh[0][0]+sh[1][0]+sh[2][0]+sh[3][0];
    double SS = sh[0][1]+sh[1][1]+sh[2][1]+sh[3][1];
    double mean = S/32768.0;
    double var  = SS/32768.0 - mean*mean;
    double inv  = 1.0/sqrt(var + 1e-5);
    double a = (double)bnw[tp]*inv;
    bnA[tp] = (float)a;
    bnB[tp] = (float)((double)bnb[tp] - mean*a);
  }
}

// ================= fused BN-apply + GRU (64 lanes per batch elem) =================
// Software-pipelined DS schedule: x(t) in registers; per step issue h-reads then
// x(t+1)-reads, compute x-dots in the h-read latency shadow. Chunk m+1 is stored
// to LDS at the TOP of chunk m's loop, chunk m+2 global-loaded into registers.
__global__ __launch_bounds__(256) void gru_kernel(
    const float* __restrict__ Xr, const float* __restrict__ Xi,
    const float* __restrict__ Wih, const float* __restrict__ Whh,
    const float* __restrict__ bih, const float* __restrict__ bhh,
    const float* __restrict__ bnA, const float* __restrict__ bnB,
    float* __restrict__ hbuf){
  const int lane = threadIdx.x & 63;
  const int wv   = threadIdx.x >> 6;
  const int b    = blockIdx.x*4 + wv;
  const int j    = lane & 31;      // output index
  const int k0   = (lane >> 5)*16; // this lane's k-half
  const int tt0  = lane >> 3;      // 0..7 : step-within-chunk of first float4
  __shared__ float xb[4][2][512];
  __shared__ float hl[4][32];

  float WI0[16], WI1[16], WI2[16], WH0[16], WH1[16], WH2[16];
  #pragma unroll
  for (int kk=0; kk<16; kk++){
    WI0[kk] = Wih[(j     )*32 + k0+kk];
    WI1[kk] = Wih[(32+j  )*32 + k0+kk];
    WI2[kk] = Wih[(64+j  )*32 + k0+kk];
    WH0[kk] = Whh[(j     )*32 + k0+kk];
    WH1[kk] = Whh[(32+j  )*32 + k0+kk];
    WH2[kk] = Whh[(64+j  )*32 + k0+kk];
  }
  const float br  = bih[j]    + bhh[j];
  const float bz  = bih[32+j] + bhh[32+j];
  const float bin = bih[64+j];
  const float bhn = bhh[64+j];
  const size_t xbase = (size_t)b*8192;

  // prologue: chunk 0 -> xb[0] (BN applied), q <- chunk 1 globals
  {
    const float* s0 = Xr + xbase;
    float4 p0 = *(const float4*)(s0 + lane*4);
    float4 p1 = *(const float4*)(s0 + 256 + lane*4);
    const float a0 = bnA[tt0],   b0 = bnB[tt0];
    const float a1 = bnA[8+tt0], b1 = bnB[8+tt0];
    p0.x = fmaf(p0.x,a0,b0); p0.y = fmaf(p0.y,a0,b0); p0.z = fmaf(p0.z,a0,b0); p0.w = fmaf(p0.w,a0,b0);
    p1.x = fmaf(p1.x,a1,b1); p1.y = fmaf(p1.y,a1,b1); p1.z = fmaf(p1.z,a1,b1); p1.w = fmaf(p1.w,a1,b1);
    *(float4*)&xb[wv][0][lane*4]       = p0;
    *(float4*)&xb[wv][0][256 + lane*4] = p1;
  }
  float4 q0, q1; float a0n, b0n, a1n, b1n;
  {
    const float* s1 = Xr + xbase + 512;   // chunk 1 = Xr row 1
    q0 = *(const float4*)(s1 + lane*4);
    q1 = *(const float4*)(s1 + 256 + lane*4);
    a0n = bnA[16+tt0]; b0n = bnB[16+tt0];
    a1n = bnA[24+tt0]; b1n = bnB[24+tt0];
  }
  hl[wv][j] = 0.f;   // lanes j and j+32 write same value: benign
  float h = 0.f;
  // xcur <- step 0 (in-order DS: reads follow the prologue stores)
  float xcur[16];
  {
    const float4 xa = *(const float4*)&xb[wv][0][k0];
    const float4 xbv= *(const float4*)&xb[wv][0][k0+4];
    const float4 xc2= *(const float4*)&xb[wv][0][k0+8];
    const float4 xd = *(const float4*)&xb[wv][0][k0+12];
    xcur[0]=xa.x; xcur[1]=xa.y; xcur[2]=xa.z; xcur[3]=xa.w;
    xcur[4]=xbv.x; xcur[5]=xbv.y; xcur[6]=xbv.z; xcur[7]=xbv.w;
    xcur[8]=xc2.x; xcur[9]=xc2.y; xcur[10]=xc2.z; xcur[11]=xc2.w;
    xcur[12]=xd.x; xcur[13]=xd.y; xcur[14]=xd.z; xcur[15]=xd.w;
  }

  for (int m=0; m<32; m++){
    const float* xc = xb[wv][m & 1];
    float* xn = xb[wv][(m+1) & 1];
    if (m < 31){   // store chunk m+1 (BN applied) at TOP of chunk loop
      q0.x = fmaf(q0.x,a0n,b0n); q0.y = fmaf(q0.y,a0n,b0n); q0.z = fmaf(q0.z,a0n,b0n); q0.w = fmaf(q0.w,a0n,b0n);
      q1.x = fmaf(q1.x,a1n,b1n); q1.y = fmaf(q1.y,a1n,b1n); q1.z = fmaf(q1.z,a1n,b1n); q1.w = fmaf(q1.w,a1n,b1n);
      *(float4*)&xn[lane*4]       = q0;
      *(float4*)&xn[256 + lane*4] = q1;
    }
    if (m < 30){   // global-load chunk m+2 into registers
      const int mm = m+2;
      const float* s2 = ((mm < 16) ? Xr : Xi) + xbase + (size_t)(mm & 15)*512;
      q0 = *(const float4*)(s2 + lane*4);
      q1 = *(const float4*)(s2 + 256 + lane*4);
      a0n = bnA[mm*16+tt0];   b0n = bnB[mm*16+tt0];
      a1n = bnA[mm*16+8+tt0]; b1n = bnB[mm*16+8+tt0];
    }
    #pragma unroll
    for (int tt=0; tt<16; tt++){
      // (a) h reads first: wait for these is lgkmcnt(4), leaving x(t+1) in flight
      const float4 ha = *(const float4*)&hl[wv][k0];
      const float4 hb = *(const float4*)&hl[wv][k0 + 4];
      const float4 hc = *(const float4*)&hl[wv][k0 + 8];
      const float4 hd = *(const float4*)&hl[wv][k0 + 12];
      // (b) x(t+1) reads issued now, consumed next step
      const bool last = (tt == 15);
      const float* xsrc = last ? xn : xc;
      const int xoff = last ? k0 : (tt+1)*32 + k0;
      float xnext[16];
      if (!last || m < 31){
        const float4 na = *(const float4*)&xsrc[xoff];
        const float4 nb = *(const float4*)&xsrc[xoff+4];
        const float4 nc = *(const float4*)&xsrc[xoff+8];
        const float4 nd = *(const float4*)&xsrc[xoff+12];
        xnext[0]=na.x; xnext[1]=na.y; xnext[2]=na.z; xnext[3]=na.w;
        xnext[4]=nb.x; xnext[5]=nb.y; xnext[6]=nb.z; xnext[7]=nb.w;
        xnext[8]=nc.x; xnext[9]=nc.y; xnext[10]=nc.z; xnext[11]=nc.w;
        xnext[12]=nd.x; xnext[13]=nd.y; xnext[14]=nd.z; xnext[15]=nd.w;
      } else {
        #pragma unroll
        for (int kk=0; kk<16; kk++) xnext[kk] = 0.f;
      }
      // (c) x-dots from registers (fills h-read latency)
      float gxr=0.f, gxz=0.f, gxn=0.f;
      #pragma unroll
      for (int kk=0; kk<16; kk++){
        gxr = fmaf(xcur[kk], WI0[kk], gxr);
        gxz = fmaf(xcur[kk], WI1[kk], gxz);
        gxn = fmaf(xcur[kk], WI2[kk], gxn);
      }
      // (d) h-dots
      float hr16[16] = {ha.x,ha.y,ha.z,ha.w, hb.x,hb.y,hb.z,hb.w,
                        hc.x,hc.y,hc.z,hc.w, hd.x,hd.y,hd.z,hd.w};
      float ghr=0.f, ghz=0.f, ghn=0.f;
      #pragma unroll
      for (int kk=0; kk<16; kk++){
        ghr = fmaf(hr16[kk], WH0[kk], ghr);
        ghz = fmaf(hr16[kk], WH1[kk], ghz);
        ghn = fmaf(hr16[kk], WH2[kk], ghn);
      }
      float grt = gxr + ghr;
      float gzt = gxz + ghz;
      grt += __shfl_xor(grt, 32, 64);
      gzt += __shfl_xor(gzt, 32, 64);
      float gnx = gxn + __shfl_xor(gxn, 32, 64);
      float hnv = ghn + __shfl_xor(ghn, 32, 64);
      const float r = __frcp_rn(1.0f + __expf(-(grt + br)));
      const float z = __frcp_rn(1.0f + __expf(-(gzt + bz)));
      const float nn = gnx + bin + r*(hnv + bhn);
      const float th = 1.0f - 2.0f*__frcp_rn(1.0f + __expf(2.0f*nn));  // tanh
      h = th + z*(h - th);
      hl[wv][j] = h;   // both halves write identical value
      #pragma unroll
      for (int kk=0; kk<16; kk++) xcur[kk] = xnext[kk];
    }
  }
  if (lane < 32) hbuf[(size_t)b*32 + j] = h;
}

// ================= h -> Rx (K matrix entries) =================
__global__ __launch_bounds__(256) void rx_kernel(
    const float* __restrict__ hbuf, const float* __restrict__ fcW,
    const float* __restrict__ fcb, float* __restrict__ Rx){
  const int b = blockIdx.x;
  __shared__ float hs[32];
  if (threadIdx.x < 32) hs[threadIdx.x] = hbuf[(size_t)b*32 + threadIdx.x];
  __syncthreads();
  for (int o = threadIdx.x; o < 512; o += 256){
    float acc = fcb[o];
    const float4* W4 = (const float4*)(fcW + o*32);
    const float4* H4 = (const float4*)hs;
    #pragma unroll
    for (int q=0; q<8; q++){
      const float4 w = W4[q], hh = H4[q];
      acc += w.x*hh.x + w.y*hh.y + w.z*hh.z + w.w*hh.w;
    }
    Rx[(size_t)b*512 + o] = acc;
  }
}

// ================= complex 16x16 eig, fp32, one wave per matrix ================
// Single-wave block: LDS ops complete in program order across the wave -> no
// __syncthreads needed; wave_barrier() is a free compiler scheduling fence.
#define LD 17
__global__ __launch_bounds__(64) void eig_kernel(
    const float* __restrict__ Rx, float* __restrict__ Un){
  __shared__ float2 T[16*LD];
  __shared__ float2 Q[16*LD];
  __shared__ float2 Y[16*LD];
  __shared__ float2 ev[16];
  const int lane = threadIdx.x;
  const int b = blockIdx.x;
  const float* rx = Rx + (size_t)b*512;

  float hn2;
  {
    const float4 re = *(const float4*)(rx + lane*4);
    const float4 im = *(const float4*)(rx + 256 + lane*4);
    const float rr[4] = {re.x, re.y, re.z, re.w};
    const float ii[4] = {im.x, im.y, im.z, im.w};
    #pragma unroll
    for (int q=0; q<4; q++){
      const int e = lane*4 + q;
      const int r = e >> 4, c = e & 15;
      T[r*LD+c] = f2(rr[q], ii[q]);
      Q[r*LD+c] = f2((r==c)?1.f:0.f, 0.f);
    }
    float hp = rr[0]*rr[0]+rr[1]*rr[1]+rr[2]*rr[2]+rr[3]*rr[3]
             + ii[0]*ii[0]+ii[1]*ii[1]+ii[2]*ii[2]+ii[3]*ii[3];
    for (int m=1; m<64; m<<=1) hp += __shfl_xor(hp, m, 64);
    hn2 = (hp == 0.f) ? 1.f : hp;
  }
  __builtin_amdgcn_wave_barrier();

  // ---- Householder Hessenberg, accumulating Q ----
  for (int k=0; k<14; k++){
    float2 xr = f2(0.f,0.f);
    if (lane >= k+1 && lane < 16) xr = T[lane*LD+k];
    float nx2 = fabs2sq(xr);
    nx2 += __shfl_xor(nx2, 1, 64);
    nx2 += __shfl_xor(nx2, 2, 64);
    nx2 += __shfl_xor(nx2, 4, 64);
    nx2 += __shfl_xor(nx2, 8, 64);
    nx2 = __shfl(nx2, lane & 15, 64);   // broadcast group sum
    if (nx2 > 1e-30f){
      const float2 alpha = T[(k+1)*LD+k];
      const float anorm = __fsqrt_rn(fabs2sq(alpha));
      const float normx = __fsqrt_rn(nx2);
      const float2 beta = (anorm > 0.f) ? fscale2(alpha, -normx/anorm) : f2(-normx, 0.f);
      const float vn2 = 2.f*nx2 + 2.f*normx*anorm;
      const float inv = __frsqrt_rn(vn2);
      float2 wvl = fscale2(xr, inv);
      if (lane == k+1) wvl = fscale2(fsub2(xr, beta), inv);
      if (lane < 16) ev[lane] = (lane >= k+1) ? wvl : f2(0.f,0.f);
      __builtin_amdgcn_wave_barrier();
      if (lane < 16){   // left: column j = lane
        float2 d = f2(0.f,0.f);
        for (int r=k+1; r<16; r++) d = fmad2(fconj2(ev[r]), T[r*LD+lane], d);
        d = fscale2(d, 2.f);
        for (int r=k+1; r<16; r++) T[r*LD+lane] = fsub2(T[r*LD+lane], fmul2(ev[r], d));
      }
      __builtin_amdgcn_wave_barrier();
      if (lane < 32){   // right: rows of T (lanes 0-15) and Q (lanes 16-31)
        const int r0 = lane & 15;
        float2* M = (lane < 16) ? T : Q;
        float2 d = f2(0.f,0.f);
        for (int r=k+1; r<16; r++) d = fmad2(M[r0*LD+r], ev[r], d);
        d = fscale2(d, 2.f);
        for (int r=k+1; r<16; r++) M[r0*LD+r] = fsub2(M[r0*LD+r], fmul2(d, fconj2(ev[r])));
      }
      __builtin_amdgcn_wave_barrier();
    }
  }

  // ---- shifted QR: ballot deflation scan, broadcast-read corners ----
  unsigned long long deflmask = 0ull;
  int hi = 15, its = 0;
  const float eps2f = 1e-9f;    // (|sd|/|sc|)^2 threshold ~ (3.2e-5)^2
  for (int tot=0; tot<72; tot++){
    float2 sub = f2(0.f,0.f), dd0 = f2(0.f,0.f), dd1 = f2(0.f,0.f);
    if (lane >= 1 && lane < 16){
      sub = T[lane*LD+lane-1];
      dd0 = T[(lane-1)*LD+(lane-1)];
      dd1 = T[lane*LD+lane];
    }
    float sc2 = fabs2sq(dd0) + fabs2sq(dd1);
    if (sc2 == 0.f) sc2 = hn2;
    const bool fdef = (lane >= 1 && lane < 16) && (fabs2sq(sub) <= eps2f*sc2);
    deflmask |= __ballot(fdef);
    while (hi > 0 && ((deflmask >> hi) & 1ull)){ hi--; its = 0; }
    if (hi <= 0) break;
    const unsigned long long m2 = deflmask & ((1ull << hi) - 1ull);
    const int lo = m2 ? (63 - __builtin_clzll(m2)) : 0;
    its++;
    // window corners + shift vector: wave-uniform broadcast LDS reads
    const float2 aa = T[(hi-1)*LD+hi-1];
    const float2 bb = T[(hi-1)*LD+hi];
    const float2 cc = T[hi*LD+hi-1];
    const float2 dd = T[hi*LD+hi];
    const float2 x0 = T[lo*LD+lo];
    const float2 y0 = T[(lo+1)*LD+lo];
    float2 mu;
    if (its % 5 == 0){
      mu = f2(dd.x + 0.75f*__fsqrt_rn(fabs2sq(cc)), dd.y);   // exceptional
    } else {
      const float2 t2 = fscale2(fsub2(aa, dd), 0.5f);
      const float2 bc = fmul2(bb, cc);
      const float2 del = csqrtf2(fadd2(fmul2(t2, t2), bc));
      const float2 d1 = fadd2(t2, del), d2v = fsub2(t2, del);
      const float2 den = (fabs2sq(d1) >= fabs2sq(d2v)) ? d1 : d2v;
      mu = (fabs2sq(den) > 0.f) ? fsub2(dd, fdivc2(bc, den)) : dd;
    }
    float2 x = fsub2(x0, mu);
    float2 y = y0;
    for (int i=lo; i<hi; i++){
      // rotation params (all lanes, redundant)
      const float ax2 = fabs2sq(x), ay2 = fabs2sq(y);
      float c_; float2 s;
      if (ax2 < 1e-30f){
        if (ay2 < 1e-37f){ c_ = 1.f; s = f2(0.f,0.f); }
        else { c_ = 0.f; s = fscale2(fconj2(y), __frsqrt_rn(ay2)); }
      } else {
        const float inv_ax = __frsqrt_rn(ax2);
        const float inv_rr = __frsqrt_rn(ax2 + ay2);
        c_ = ax2*inv_ax*inv_rr;   // = |x| / r
        s = fscale2(fmul2(x, fconj2(y)), inv_ax*inv_rr);
      }
      // role partition: 0 = row-update, 1 = T col-update, 2 = Q col-update,
      // 3 (lanes 48-51) = 2x2 intersection
      const int q16 = lane & 15;
      const int role = lane >> 4;
      float2* Mp = (role == 2) ? Q : T;
      int ia = 0, ib = 0; bool active = false;
      if (role == 0){ ia = i*LD+q16; ib = (i+1)*LD+q16; active = (q16!=i)&&(q16!=i+1); }
      else if (role == 1){ ia = q16*LD+i; ib = ia+1; active = (q16!=i)&&(q16!=i+1); }
      else if (role == 2){ ia = q16*LD+i; ib = ia+1; active = true; }
      if (active){
        const float2 A = Mp[ia], B = Mp[ib];
        const float2 sl = (role == 0) ? s : fconj2(s);
        Mp[ia] = fadd2(fscale2(A, c_), fmul2(sl, B));
        Mp[ib] = fsub2(fscale2(B, c_), fmul2(fconj2(sl), A));
      }
      if (role == 3 && q16 < 4){   // 4 lanes: broadcast-read 2x2, each writes one entry
        const float2 t00 = T[i*LD+i],     t01 = T[i*LD+i+1];
        const float2 t10 = T[(i+1)*LD+i], t11 = T[(i+1)*LD+i+1];
        const float2 r0c0 = fadd2(fscale2(t00, c_), fmul2(s, t10));
        const float2 r0c1 = fadd2(fscale2(t01, c_), fmul2(s, t11));
        const float2 r1c0 = fsub2(fscale2(t10, c_), fmul2(fconj2(s), t00));
        const float2 r1c1 = fsub2(fscale2(t11, c_), fmul2(fconj2(s), t01));
        float2 outv;
        if (q16 == 0)      outv = fadd2(fscale2(r0c0, c_), fmul2(fconj2(s), r0c1));
        else if (q16 == 1) outv = fsub2(fscale2(r0c1, c_), fmul2(s, r0c0));
        else if (q16 == 2) outv = fadd2(fscale2(r1c0, c_), fmul2(fconj2(s), r1c1));
        else               outv = fsub2(fscale2(r1c1, c_), fmul2(s, r1c0));
        T[(i+(q16>>1))*LD + (i+(q16&1))] = outv;
      }
      __builtin_amdgcn_wave_barrier();
      if (i < hi-1){
        x = T[(i+1)*LD+i];   // in-order LDS read-back (same-wave DS ordering)
        y = T[(i+2)*LD+i];
      }
    }
  }
  __builtin_amdgcn_wave_barrier();

  // ---- eigenvectors: backsolve on triangular T, then V = Q*Y ----
  if (lane < 16) ev[lane] = T[lane*LD+lane];
  __builtin_amdgcn_wave_barrier();
  const float hnf = __fsqrt_rn(hn2);
  const float smin = 1e-6f*hnf + 1e-35f;
  if (lane < 16){
    const int i = lane;
    const float2 lam = ev[i];
    Y[i*LD+i] = f2(1.f, 0.f);
    for (int jj=i-1; jj>=0; jj--){
      float2 sum = f2(0.f,0.f);
      for (int k2=jj+1; k2<=i; k2++) sum = fmad2(T[jj*LD+k2], Y[k2*LD+i], sum);
      float2 den = fsub2(T[jj*LD+jj], lam);
      if (fabs2sq(den) < smin*smin) den = f2(smin, 0.f);
      Y[jj*LD+i] = fdivc2(f2(-sum.x, -sum.y), den);
    }
  }
  __builtin_amdgcn_wave_barrier();
  {
    const int i = lane & 15;       // eigenvector index
    const int g = lane >> 4;       // row-group: rows 4g..4g+3
    float2 v[4]; float nrm = 0.f;
    #pragma unroll
    for (int q=0; q<4; q++){
      const int n = 4*g + q;
      float2 acc = f2(0.f,0.f);
      for (int k2=0; k2<=i; k2++) acc = fmad2(Q[n*LD+k2], Y[k2*LD+i], acc);
      v[q] = acc; nrm += fabs2sq(acc);
    }
    nrm += __shfl_xor(nrm, 16, 64);
    nrm += __shfl_xor(nrm, 32, 64);
    const float inv = __frsqrt_rn(nrm);
    const float mi = fabs2sq(ev[i]);
    int rank = 0;
    for (int k2=0; k2<16; k2++){
      const float mk = fabs2sq(ev[k2]);
      rank += (mk > mi) || (mk == mi && k2 > i);
    }
    if (rank >= 3){
      float* dst = Un + ((size_t)b*NOISE_K + (rank-3))*32 + 8*g;
      float4 w0, w1;
      w0.x = v[0].x*inv; w0.y = v[0].y*inv;
      w0.z = v[1].x*inv; w0.w = v[1].y*inv;
      w1.x = v[2].x*inv; w1.y = v[2].y*inv;
      w1.z = v[3].x*inv; w1.w = v[3].y*inv;
      ((float4*)dst)[0] = w0;
      ((float4*)dst)[1] = w1;
    }
  }
}

// ================= MUSIC spectrum + MLP head =================
__global__ __launch_bounds__(256) void spec_head_kernel(
    const float* __restrict__ Un, const float* __restrict__ CA,
    const float* __restrict__ fc1T, const float* __restrict__ fc1b,
    const float* __restrict__ fc2W, const float* __restrict__ fc2b,
    const float* __restrict__ fc3W, const float* __restrict__ fc3b,
    float* __restrict__ out){
  const int b = blockIdx.x;
  const int tid = threadIdx.x;
  __shared__ float2 Us[NOISE_K*16];
  __shared__ float spec[N_ANGLES];
  __shared__ float y1[32], y2[32];
  if (tid < NOISE_K*16) Us[tid] = ((const float2*)Un)[(size_t)b*NOISE_K*16 + tid];
  __syncthreads();
  for (int a = tid; a < N_ANGLES; a += 256){
    float sr[NOISE_K], si[NOISE_K];
    #pragma unroll
    for (int k=0; k<NOISE_K; k++){ sr[k]=0.f; si[k]=0.f; }
    for (int n=0; n<16; n++){
      float2 ca = ((const float2*)CA)[a*16+n];
      #pragma unroll
      for (int k=0; k<NOISE_K; k++){
        float2 u = Us[k*16+n];
        sr[k] += ca.x*u.x - ca.y*u.y;
        si[k] += ca.x*u.y + ca.y*u.x;
      }
    }
    float d = 0.f;
    #pragma unroll
    for (int k=0; k<NOISE_K; k++) d += sr[k]*sr[k] + si[k]*si[k];
    spec[a] = 1.0f/d;
  }
  __syncthreads();
  if (tid < 32){
    float acc = fc1b[tid];
    for (int a=0; a<N_ANGLES; a++) acc += spec[a]*fc1T[a*32+tid];
    y1[tid] = fmaxf(acc, 0.f);
  }
  __syncthreads();
  if (tid < 32){
    float acc = fc2b[tid];
    #pragma unroll
    for (int k=0; k<32; k++) acc += y1[k]*fc2W[tid*32+k];
    y2[tid] = fmaxf(acc, 0.f);
  }
  __syncthreads();
  if (tid < 32){
    float acc = fc2b[tid];
    #pragma unroll
    for (int k=0; k<32; k++) acc += y2[k]*fc2W[tid*32+k];
    y1[tid] = fmaxf(acc, 0.f);
  }
  __syncthreads();
  if (tid < 3){
    float acc = fc3b[tid];
    #pragma unroll
    for (int k=0; k<32; k++) acc += y1[k]*fc3W[tid*32+k];
    out[(size_t)b*3 + tid] = acc;
  }
}

// ================= launcher =================
extern "C" void kernel_launch(void* const* d_in, const int* in_sizes, int n_in,
                              void* d_out, int out_size, void* d_ws, size_t ws_size,
                              hipStream_t stream){
  (void)in_sizes; (void)n_in; (void)out_size; (void)ws_size;
  const float* Xr   = (const float*)d_in[0];
  const float* Xi   = (const float*)d_in[1];
  const float* bnw  = (const float*)d_in[2];
  const float* bnb  = (const float*)d_in[3];
  const float* Wih  = (const float*)d_in[4];
  const float* Whh  = (const float*)d_in[5];
  const float* bih  = (const float*)d_in[6];
  const float* bhh  = (const float*)d_in[7];
  const float* fcW  = (const float*)d_in[8];
  const float* fcb  = (const float*)d_in[9];
  const float* fc1W = (const float*)d_in[10];
  const float* fc1b = (const float*)d_in[11];
  const float* fc2W = (const float*)d_in[12];
  const float* fc2b = (const float*)d_in[13];
  const float* fc3W = (const float*)d_in[14];
  const float* fc3b = (const float*)d_in[15];

  float* ws   = (float*)d_ws;
  float* bnA  = ws + WS_BNA;
  float* bnB  = ws + WS_BNB;
  float* hbuf = ws + WS_H;
  float* RxB  = ws + WS_RX;
  float* CA   = ws + WS_CA;
  float* fc1T = ws + WS_FC1T;
  float* UnB  = ws + WS_UN;

  hipLaunchKernelGGL(prep_kernel, dim3(45), dim3(256), 0, stream, fc1W, CA, fc1T);
  hipLaunchKernelGGL(bn_stats_kernel, dim3(512), dim3(256), 0, stream,
                     Xr, Xi, bnw, bnb, bnA, bnB);
  hipLaunchKernelGGL(gru_kernel, dim3(256), dim3(256), 0, stream,
                     Xr, Xi, Wih, Whh, bih, bhh, bnA, bnB, hbuf);
  hipLaunchKernelGGL(rx_kernel, dim3(1024), dim3(256), 0, stream,
                     hbuf, fcW, fcb, RxB);
  hipLaunchKernelGGL(eig_kernel, dim3(1024), dim3(64), 0, stream, RxB, UnB);
  hipLaunchKernelGGL(spec_head_kernel, dim3(1024), dim3(256), 0, stream,
                     UnB, CA, fc1T, fc1b, fc2W, fc2b, fc3W, fc3b, (float*)d_out);
}